// Round 5
// baseline (2332.733 us; speedup 1.0000x reference)
//
#include <hip/hip_runtime.h>
#include <cmath>

static constexpr int NN = 50000;   // nodes
static constexpr int EE = 500000;  // edges

typedef short v8s __attribute__((ext_vector_type(8)));
typedef short v4s __attribute__((ext_vector_type(4)));
typedef float v4f __attribute__((ext_vector_type(4)));

__device__ inline short f2bf(float x){
  union{float f; unsigned u;} v{x};
  unsigned r = v.u + 0x7fffu + ((v.u >> 16) & 1u);
  return (short)(r >> 16);
}
__device__ inline float b2f(short s){
  union{unsigned u; float f;} v; v.u = ((unsigned)(unsigned short)s) << 16; return v.f;
}

// ---------------- graph prep ----------------

__global__ __launch_bounds__(256)
void count_deg_k(const int* __restrict__ dst, int* __restrict__ cnt, int e_total){
  int e = blockIdx.x*256 + threadIdx.x;
  if (e < e_total) atomicAdd(&cnt[dst[e]], 1);
}

__global__ __launch_bounds__(1024)
void scan_block_k(const int* __restrict__ cnt, int* __restrict__ pre,
                  int* __restrict__ bsum, int n){
  __shared__ int tmp[1024];
  int b = blockIdx.x, t = threadIdx.x, i = b*1024 + t;
  int v = (i < n) ? cnt[i] : 0;
  tmp[t] = v; __syncthreads();
  for (int off = 1; off < 1024; off <<= 1){
    int u = (t >= off) ? tmp[t-off] : 0;
    __syncthreads();
    tmp[t] += u;
    __syncthreads();
  }
  if (i < n) pre[i] = tmp[t];
  if (t == 1023) bsum[b] = tmp[t];
}

__global__ void scan_sums_k(int* __restrict__ bsum, int nb){
  if (threadIdx.x == 0){
    int s = 0;
    for (int i = 0; i < nb; i++){ int v = bsum[i]; bsum[i] = s; s += v; }
  }
}

__global__ __launch_bounds__(256)
void scan_finalize_k(const int* __restrict__ pre, const int* __restrict__ bsum,
                     int* __restrict__ offs, int n){
  int i = blockIdx.x*256 + threadIdx.x;
  if (i < n) offs[i+1] = pre[i] + bsum[i >> 10];
  if (i == 0) offs[0] = 0;
}

__global__ __launch_bounds__(256)
void fill_csr_k(const int* __restrict__ dst, const int* __restrict__ src,
                const int* __restrict__ offs, int* __restrict__ cursor,
                int* __restrict__ eids, int* __restrict__ srcs_csr, int e_total){
  int e = blockIdx.x*256 + threadIdx.x;
  if (e < e_total){
    int d = dst[e];
    int p = offs[d] + atomicAdd(&cursor[d], 1);
    eids[p] = e;
    srcs_csr[p] = src[e];
  }
}

// ---------------- small fp32 helpers (weight prep) ----------------

__global__ __launch_bounds__(128)
void vecmat_bias_k(const float* __restrict__ v, const float* __restrict__ B,
                   const float* __restrict__ b2, float* __restrict__ out, int K, int Nc){
  int c = blockIdx.x*128 + threadIdx.x;
  if (c < Nc){
    float s = b2[c];
    for (int k = 0; k < K; k++) s += v[k]*B[(size_t)k*Nc + c];
    out[c] = s;
  }
}

__global__ __launch_bounds__(256)
void sgemm_k(const float* __restrict__ A, const float* __restrict__ B,
             float* __restrict__ C, int M, int K, int Nc){
  __shared__ float As[16][65];
  __shared__ float Bs[16][65];
  int bm = blockIdx.x*64, bn = blockIdx.y*64;
  int tid = threadIdx.x;
  int tx = tid & 15, ty = tid >> 4;
  float acc[4][4] = {};
  for (int k0 = 0; k0 < K; k0 += 16){
    #pragma unroll
    for (int i = 0; i < 4; i++){
      int t = tid + 256*i;
      int r = t >> 4, c = t & 15;
      int gr = bm + r, gc = k0 + c;
      As[c][r] = (gr < M && gc < K) ? A[(size_t)gr*K + gc] : 0.f;
    }
    #pragma unroll
    for (int i = 0; i < 4; i++){
      int t = tid + 256*i;
      int r = t >> 6, c = t & 63;
      int gr = k0 + r, gc = bn + c;
      Bs[r][c] = (gr < K && gc < Nc) ? B[(size_t)gr*Nc + gc] : 0.f;
    }
    __syncthreads();
    #pragma unroll
    for (int kk = 0; kk < 16; kk++){
      float a[4], b[4];
      #pragma unroll
      for (int i = 0; i < 4; i++) a[i] = As[kk][ty*4 + i];
      #pragma unroll
      for (int j = 0; j < 4; j++) b[j] = Bs[kk][tx*4 + j];
      #pragma unroll
      for (int i = 0; i < 4; i++)
        #pragma unroll
        for (int j = 0; j < 4; j++) acc[i][j] += a[i]*b[j];
    }
    __syncthreads();
  }
  #pragma unroll
  for (int i = 0; i < 4; i++){
    int gr = bm + ty*4 + i;
    if (gr >= M) continue;
    #pragma unroll
    for (int j = 0; j < 4; j++){
      int gc = bn + tx*4 + j;
      if (gc < Nc) C[(size_t)gr*Nc + gc] = acc[i][j];
    }
  }
}

// transpose+convert weights: dst[c][k] = src[k][c], bf16, zero-padded to Kpad
__global__ __launch_bounds__(256)
void tconv_k(const float* __restrict__ src, int K, int ldsrc, int Ncols,
             short* __restrict__ dst, int Kpad){
  int c = blockIdx.x;
  int k = blockIdx.y*256 + threadIdx.x;
  if (c < Ncols && k < Kpad)
    dst[(long)c*Kpad + k] = (k < K) ? f2bf(src[(long)k*ldsrc + c]) : (short)0;
}

// B' for post GEMM
__global__ __launch_bounds__(256)
void btpost_k(const float* __restrict__ Wpost, int F, int Kpad,
              short* __restrict__ dst){
  int cp = blockIdx.x;                 // 0..399
  int k = blockIdx.y*256 + threadIdx.x;
  if (k >= Kpad) return;
  int g = cp / 80, c = cp - g*80;
  float v = 0.f;
  if (k < F){ if (g == 0) v = Wpost[(long)k*80 + c]; }
  else if (k < 7*F) v = Wpost[(long)(F + g*6*F + (k - F))*80 + c];
  dst[(long)cp*Kpad + k] = f2bf(v);
}

__global__ __launch_bounds__(256)
void cvt_rows_k(const float* __restrict__ src, int K, short* __restrict__ dst,
                int ldd, long total){
  long i = (long)blockIdx.x*256 + threadIdx.x;
  if (i >= total) return;
  int n = (int)(i / K), c = (int)(i - (long)n*K);
  dst[(long)n*ldd + c] = f2bf(src[i]);
}

// ---------------- persistent-B MFMA GEMM (K <= 128, Bt: [ncols][128] bf16) ------
// A direct global->register fragments, SEQUENTIAL rows (no gather).
// Each wave owns 32 rows per tile; 8 waves/block; grid-stride over tiles.
// Output split: col < split -> C1 (C_F32 selects dtype), else C2 (bf16).
template<int NFR, bool A_F32, bool C_F32, bool RELU>
__global__ __launch_bounds__(512)
void egemm_k(const void* __restrict__ Av, long lda, int Kreal,
             const short* __restrict__ Bt, const float* __restrict__ bias,
             void* __restrict__ C1v, long ld1,
             short* __restrict__ C2, long ld2, int split,
             int M, int ncols)
{
  constexpr int BN = NFR*16;
  __shared__ short Bs[BN][136];
  const float* Af = (const float*)Av;
  const short* Ab = (const short*)Av;
  float* C1f = (float*)C1v; short* C1b = (short*)C1v;

  for (int u = threadIdx.x; u < BN*16; u += 512){
    int c = u >> 4, k8 = (u & 15)*8;
    v8s vv = (v8s)0;
    if (c < ncols) vv = *(const v8s*)(Bt + (long)c*128 + k8);
    *(v8s*)&Bs[c][k8] = vv;
  }
  __syncthreads();

  int lane = threadIdx.x & 63;
  int lr = lane & 15, lkg = lane >> 4;
  int w0 = (blockIdx.x*512 + threadIdx.x) >> 6;
  int nw = gridDim.x * 8;
  int Mtiles = (M + 31) >> 5;

  for (int t = w0; t < Mtiles; t += nw){
    int base = t*32;
    long r0 = base + lr;      if (r0 > M-1) r0 = M-1;
    long r1 = base + 16 + lr; if (r1 > M-1) r1 = M-1;

    v8s a0[4], a1[4];
    if constexpr (A_F32){
      const float* p0 = Af + r0*lda;
      const float* p1 = Af + r1*lda;
      #pragma unroll
      for (int ks = 0; ks < 4; ks++){
        int kb = ks*32 + lkg*8;
        v8s o0 = (v8s)0, o1 = (v8s)0;
        if (kb + 3 < Kreal){
          float4 f0 = *(const float4*)(p0 + kb);
          float4 f1 = *(const float4*)(p1 + kb);
          o0[0]=f2bf(f0.x); o0[1]=f2bf(f0.y); o0[2]=f2bf(f0.z); o0[3]=f2bf(f0.w);
          o1[0]=f2bf(f1.x); o1[1]=f2bf(f1.y); o1[2]=f2bf(f1.z); o1[3]=f2bf(f1.w);
        }
        if (kb + 7 < Kreal){
          float4 f0 = *(const float4*)(p0 + kb + 4);
          float4 f1 = *(const float4*)(p1 + kb + 4);
          o0[4]=f2bf(f0.x); o0[5]=f2bf(f0.y); o0[6]=f2bf(f0.z); o0[7]=f2bf(f0.w);
          o1[4]=f2bf(f1.x); o1[5]=f2bf(f1.y); o1[6]=f2bf(f1.z); o1[7]=f2bf(f1.w);
        }
        a0[ks] = o0; a1[ks] = o1;
      }
    } else {
      const short* p0 = Ab + r0*lda + lkg*8;
      const short* p1 = Ab + r1*lda + lkg*8;
      #pragma unroll
      for (int ks = 0; ks < 4; ks++){
        a0[ks] = *(const v8s*)(p0 + ks*32);
        a1[ks] = *(const v8s*)(p1 + ks*32);
      }
    }

    v4f acc0[NFR], acc1[NFR];
    #pragma unroll
    for (int n = 0; n < NFR; n++){ acc0[n] = (v4f)0.f; acc1[n] = (v4f)0.f; }
    #pragma unroll
    for (int ks = 0; ks < 4; ks++){
      #pragma unroll
      for (int n = 0; n < NFR; n++){
        v8s b = *(const v8s*)&Bs[n*16 + lr][ks*32 + lkg*8];
        acc0[n] = __builtin_amdgcn_mfma_f32_16x16x32_bf16(a0[ks], b, acc0[n], 0, 0, 0);
        acc1[n] = __builtin_amdgcn_mfma_f32_16x16x32_bf16(a1[ks], b, acc1[n], 0, 0, 0);
      }
    }
    // epilogue: col = n*16 + lr ; row = base + m*16 + lkg*4 + j
    #pragma unroll
    for (int n = 0; n < NFR; n++){
      int col = n*16 + lr;
      if (col >= ncols) continue;
      float bv = bias ? bias[col] : 0.f;
      #pragma unroll
      for (int j = 0; j < 4; j++){
        int row = base + lkg*4 + j;
        if (row < M){
          float v = acc0[n][j] + bv;
          if (RELU) v = fmaxf(v, 0.f);
          if (col < split){
            if constexpr (C_F32) C1f[(long)row*ld1 + col] = v;
            else                 C1b[(long)row*ld1 + col] = f2bf(v);
          } else C2[(long)row*ld2 + (col - split)] = f2bf(v);
        }
        int row1 = row + 16;
        if (row1 < M){
          float v = acc1[n][j] + bv;
          if (RELU) v = fmaxf(v, 0.f);
          if (col < split){
            if constexpr (C_F32) C1f[(long)row1*ld1 + col] = v;
            else                 C1b[(long)row1*ld1 + col] = f2bf(v);
          } else C2[(long)row1*ld2 + (col - split)] = f2bf(v);
        }
      }
    }
  }
}

// ---------------- MFMA GEMM with LDS A (for K>128: the post GEMMs) ----------------
template<int NFR>
__global__ __launch_bounds__(256)
void mgemm_k(const short* __restrict__ Ab, long lda,
             const short* __restrict__ Bt, int Kpad,
             short* __restrict__ Cb, long ldc, int M, int K, int Ncols)
{
  constexpr int BN = NFR*16;
  __shared__ short As[128][72];
  __shared__ short Bs[BN][72];

  int bm = blockIdx.x*128;
  int bn = blockIdx.y*BN;
  int tid = threadIdx.x;
  int w = tid >> 6, lane = tid & 63;
  int lr = lane & 15, lkg = lane >> 4;

  v4f acc[2][NFR];
  #pragma unroll
  for (int m = 0; m < 2; m++)
    #pragma unroll
    for (int n = 0; n < NFR; n++) acc[m][n] = (v4f)0.f;

  for (int k0 = 0; k0 < K; k0 += 64){
    #pragma unroll
    for (int p = 0; p < 4; p++){
      int u = tid + 256*p;
      int r = u >> 3, c8 = u & 7;
      int k = k0 + c8*8;
      int grow = bm + r;
      v8s out = (v8s)0;
      if (grow < M) out = *(const v8s*)(Ab + (long)grow*lda + k);
      *(v8s*)&As[r][c8*8] = out;
    }
    #pragma unroll
    for (int u0 = 0; u0 < BN*8; u0 += 256){
      int u = u0 + tid;
      if (u < BN*8){
        int c = u >> 3, k8 = (u & 7)*8;
        v8s out = (v8s)0;
        int gc = bn + c;
        if (gc < Ncols) out = *(const v8s*)(Bt + (long)gc*Kpad + k0 + k8);
        *(v8s*)&Bs[c][k8] = out;
      }
    }
    __syncthreads();
    #pragma unroll
    for (int ks = 0; ks < 2; ks++){
      v8s a0 = *(const v8s*)&As[w*32 + lr][ks*32 + lkg*8];
      v8s a1 = *(const v8s*)&As[w*32 + 16 + lr][ks*32 + lkg*8];
      #pragma unroll
      for (int n = 0; n < NFR; n++){
        v8s b = *(const v8s*)&Bs[n*16 + lr][ks*32 + lkg*8];
        acc[0][n] = __builtin_amdgcn_mfma_f32_16x16x32_bf16(a0, b, acc[0][n], 0, 0, 0);
        acc[1][n] = __builtin_amdgcn_mfma_f32_16x16x32_bf16(a1, b, acc[1][n], 0, 0, 0);
      }
    }
    __syncthreads();
  }
  #pragma unroll
  for (int m = 0; m < 2; m++){
    int row0 = bm + w*32 + m*16 + lkg*4;
    #pragma unroll
    for (int n = 0; n < NFR; n++){
      int col = bn + n*16 + lr;
      if (col >= Ncols) continue;
      #pragma unroll
      for (int j = 0; j < 4; j++){
        int row = row0 + j;
        if (row < M) Cb[(long)row*ldc + col] = f2bf(acc[m][n][j]);
      }
    }
  }
}

// ---------------- per-node aggregation (one wave per node) ----------------
// ep rows are in EDGE order; gathered via eids[p].
template<int F>
__global__ __launch_bounds__(256)
void aggregate_k(const short* __restrict__ xixj, int ldx,
                 const short* __restrict__ epc, const int* __restrict__ eids,
                 const int* __restrict__ offs, const int* __restrict__ srcs_csr,
                 short* __restrict__ aggout, long ldk,
                 float* __restrict__ scl, float avg_lin, float avg_log, int n){
  int wnode = (blockIdx.x*256 + threadIdx.x) >> 6;
  int lane = threadIdx.x & 63;
  if (wnode >= n) return;
  constexpr int C2 = F - 64;
  int beg = offs[wnode], end = offs[wnode+1];
  float xi0 = b2f(xixj[(long)wnode*ldx + lane]);
  float xi1 = (lane < C2) ? b2f(xixj[(long)wnode*ldx + 64 + lane]) : 0.f;
  float s0 = 0.f, q0 = 0.f, mn0 = INFINITY, mx0 = -INFINITY;
  float s1 = 0.f, q1 = 0.f, mn1 = INFINITY, mx1 = -INFINITY;
  for (int p = beg; p < end; p++){
    int s = srcs_csr[p];
    long e = eids[p];
    float h0 = xi0 + b2f(xixj[(long)s*ldx + F + lane]) + b2f(epc[e*F + lane]);
    s0 += h0; q0 += h0*h0; mn0 = fminf(mn0, h0); mx0 = fmaxf(mx0, h0);
    if (lane < C2){
      float h1 = xi1 + b2f(xixj[(long)s*ldx + F + 64 + lane]) + b2f(epc[e*F + 64 + lane]);
      s1 += h1; q1 += h1*h1; mn1 = fminf(mn1, h1); mx1 = fmaxf(mx1, h1);
    }
  }
  int cnt = end - beg;
  float deg = (float)(cnt > 1 ? cnt : 1);
  if (cnt == 0){ mn0 = 0.f; mx0 = 0.f; mn1 = 0.f; mx1 = 0.f; }
  float mean0 = s0/deg, var0 = q0/deg - mean0*mean0;
  float std0 = sqrtf(fmaxf(var0, 0.f) + 1e-5f);
  short* a = aggout + (long)wnode*ldk;
  a[lane] = f2bf(s0); a[F+lane] = f2bf(mean0); a[2*F+lane] = f2bf(mn0);
  a[3*F+lane] = f2bf(mx0); a[4*F+lane] = f2bf(var0); a[5*F+lane] = f2bf(std0);
  if (lane < C2){
    float mean1 = s1/deg, var1 = q1/deg - mean1*mean1;
    float std1 = sqrtf(fmaxf(var1, 0.f) + 1e-5f);
    int l2 = 64 + lane;
    a[l2] = f2bf(s1); a[F+l2] = f2bf(mean1); a[2*F+l2] = f2bf(mn1);
    a[3*F+l2] = f2bf(mx1); a[4*F+l2] = f2bf(var1); a[5*F+l2] = f2bf(std1);
  }
  if (lane == 0){
    float logd = logf(deg + 1.f);
    scl[wnode*5+0] = 1.f;
    scl[wnode*5+1] = logd/avg_log;
    scl[wnode*5+2] = avg_log/logd;
    scl[wnode*5+3] = deg/avg_lin;
    scl[wnode*5+4] = avg_lin/deg;
  }
}

// ---------------- combine: tpost[n][c] (ld 128) = bias[c] + sum_g scl[n][g]*Y[n][80g+c]
__global__ __launch_bounds__(256)
void combine_k(const short* __restrict__ Y, const float* __restrict__ scl,
               const float* __restrict__ bias, short* __restrict__ out, int total){
  int idx = blockIdx.x*256 + threadIdx.x;
  if (idx >= total) return;
  int n = idx / 80, c = idx - n*80;
  const short* y = Y + (long)n*400;
  const float* s = scl + (long)n*5;
  float v = bias[c];
  #pragma unroll
  for (int g = 0; g < 5; g++) v += s[g]*b2f(y[g*80 + c]);
  out[(long)n*128 + c] = f2bf(v);
}

// ---------------- host orchestration ----------------

extern "C" void kernel_launch(void* const* d_in, const int* in_sizes, int n_in,
                              void* d_out, int out_size, void* d_ws, size_t ws_size,
                              hipStream_t stream){
  const float* x1   = (const float*)d_in[0];
  const int*   ei1  = (const int*)  d_in[1];
  const float* ea1  = (const float*)d_in[2];
  const float* x2   = (const float*)d_in[3];
  const int*   ei2  = (const int*)  d_in[4];
  const float* ea2  = (const float*)d_in[5];
  const float* We1  = (const float*)d_in[6],  *be1   = (const float*)d_in[7];
  const float* Wpre1= (const float*)d_in[8],  *bpre1 = (const float*)d_in[9];
  const float* Wpost1=(const float*)d_in[10], *bpost1= (const float*)d_in[11];
  const float* Wlin1= (const float*)d_in[12], *blin1 = (const float*)d_in[13];
  const float* We2  = (const float*)d_in[14], *be2   = (const float*)d_in[15];
  const float* Wpre2= (const float*)d_in[16], *bpre2 = (const float*)d_in[17];
  const float* Wpost2=(const float*)d_in[18], *bpost2= (const float*)d_in[19];
  const float* Wlin2= (const float*)d_in[20], *blin2 = (const float*)d_in[21];
  const float* Wfc1 = (const float*)d_in[22], *bfc1  = (const float*)d_in[23];
  const float* Wfc2 = (const float*)d_in[24], *bfc2  = (const float*)d_in[25];

  static const double HIST[19] = {240,328,79,39,23,12,11,7,6,5,7,3,1,0,2,0,0,0,1};
  double tot = 0, lin = 0, lg = 0;
  for (int i = 0; i < 19; i++){ tot += HIST[i]; lin += i*HIST[i]; lg += log((double)i + 1.0)*HIST[i]; }
  float avg_lin = (float)(lin/tot), avg_log = (float)(lg/tot);

  const int KP1 = 704, KP2 = 576;   // post GEMM K paddings

  uintptr_t pw = (uintptr_t)d_ws;
  auto carve = [&](size_t b)->void*{ void* r = (void*)pw; pw += (b + 255) & ~(size_t)255; return r; };
  int*   cnt      = (int*)  carve((size_t)NN*4);
  int*   pre      = (int*)  carve((size_t)NN*4);
  int*   bsum     = (int*)  carve(64*4);
  int*   offs     = (int*)  carve((size_t)(NN+1)*4);
  int*   cursor   = (int*)  carve((size_t)NN*4);
  int*   eids     = (int*)  carve((size_t)EE*4);
  int*   srcs_csr = (int*)  carve((size_t)EE*4);
  float* WecA     = (float*)carve(100*100*4);
  float* WecB     = (float*)carve(100*80*4);
  float* Wlf      = (float*)carve(80*80*4);
  float* becf     = (float*)carve(256*4);
  float* blf      = (float*)carve(128*4);
  short* Btep12   = (short*)carve((size_t)180*128*2);
  short* Btij1    = (short*)carve((size_t)200*128*2);
  short* Btij2    = (short*)carve((size_t)160*128*2);
  short* Btpost1  = (short*)carve((size_t)400*KP1*2);
  short* Btpost2  = (short*)carve((size_t)400*KP2*2);
  short* Btlin1   = (short*)carve((size_t)80*128*2);
  short* Btlf     = (short*)carve((size_t)80*128*2);
  short* Btfc2    = (short*)carve((size_t)80*128*2);
  short* Aprime1  = (short*)carve((size_t)NN*KP1*2);   // [x(100) | agg(600) | pad]
  short* Aprime2  = (short*)carve((size_t)NN*KP2*2);   // [x(80)  | agg(480) | pad]
  short* xixjb    = (short*)carve((size_t)NN*200*2);
  short* epb1     = (short*)carve((size_t)EE*100*2);
  short* epb2     = (short*)carve((size_t)EE*80*2);
  float* scl      = (float*)carve((size_t)NN*5*4);
  short* Yb       = (short*)carve((size_t)NN*400*2);
  short* tpost    = (short*)carve((size_t)NN*128*2);
  short* tD       = (short*)carve((size_t)NN*128*2);

  dim3 blk(256);
  const int NB = (NN + 1023)/1024;
  const int NTILES = (NN + 31)/32;               // 1563
  const int GB_N  = (NTILES + 7)/8;              // node-GEMM blocks (1 tile/wave)
  const int GB_E  = 1024;                        // edge-GEMM blocks (grid-stride)

  // ---- weight prep ----
  sgemm_k<<<dim3(2,2), blk, 0, stream>>>(We1, Wpre1 + 2*100*100, WecA, 100, 100, 100);
  sgemm_k<<<dim3(2,2), blk, 0, stream>>>(We2, Wpre2 + 2*80*80,  WecB, 100, 80, 80);
  sgemm_k<<<dim3(2,2), blk, 0, stream>>>(Wlin2, Wfc1, Wlf, 80, 80, 80);
  vecmat_bias_k<<<dim3(1), dim3(128), 0, stream>>>(be1, Wpre1 + 2*100*100, bpre1, becf, 100, 100);
  vecmat_bias_k<<<dim3(1), dim3(128), 0, stream>>>(be2, Wpre2 + 2*80*80,  bpre2, becf + 100, 80, 80);
  vecmat_bias_k<<<dim3(1), dim3(128), 0, stream>>>(blin2, Wfc1, bfc1, blf, 80, 80);
  tconv_k<<<dim3(100,1), blk, 0, stream>>>(WecA, 100, 100, 100, Btep12, 128);
  tconv_k<<<dim3(80,1),  blk, 0, stream>>>(WecB, 100,  80,  80, Btep12 + 100*128, 128);
  tconv_k<<<dim3(100,1), blk, 0, stream>>>(Wpre1,           100, 100, 100, Btij1,           128);
  tconv_k<<<dim3(100,1), blk, 0, stream>>>(Wpre1 + 100*100, 100, 100, 100, Btij1 + 100*128, 128);
  tconv_k<<<dim3(80,1),  blk, 0, stream>>>(Wpre2,           80, 80, 80, Btij2,          128);
  tconv_k<<<dim3(80,1),  blk, 0, stream>>>(Wpre2 + 80*80,   80, 80, 80, Btij2 + 80*128, 128);
  btpost_k<<<dim3(400,(KP1+255)/256), blk, 0, stream>>>(Wpost1, 100, KP1, Btpost1);
  btpost_k<<<dim3(400,(KP2+255)/256), blk, 0, stream>>>(Wpost2,  80, KP2, Btpost2);
  tconv_k<<<dim3(80,1), blk, 0, stream>>>(Wlin1, 80, 80, 80, Btlin1, 128);
  tconv_k<<<dim3(80,1), blk, 0, stream>>>(Wlf,   80, 80, 80, Btlf,   128);
  tconv_k<<<dim3(80,1), blk, 0, stream>>>(Wfc2,  80, 80, 80, Btfc2,  128);
  // zero padded A-side buffers once (pad columns must stay 0)
  hipMemsetAsync(Aprime1, 0, (size_t)NN*KP1*2, stream);
  hipMemsetAsync(Aprime2, 0, (size_t)NN*KP2*2, stream);
  hipMemsetAsync(tpost,   0, (size_t)NN*128*2, stream);
  hipMemsetAsync(tD,      0, (size_t)NN*128*2, stream);

  for (int b = 0; b < 2; b++){
    const float* x  = b ? x2  : x1;
    const int*   ei = b ? ei2 : ei1;
    const float* ea = b ? ea2 : ea1;
    float* outb = (float*)d_out + (size_t)b*NN*80;
    const int* src = ei;
    const int* dst = ei + EE;

    // CSR
    hipMemsetAsync(cnt, 0, (size_t)NN*4, stream);
    hipMemsetAsync(cursor, 0, (size_t)NN*4, stream);
    count_deg_k<<<dim3((EE+255)/256), blk, 0, stream>>>(dst, cnt, EE);
    scan_block_k<<<dim3(NB), dim3(1024), 0, stream>>>(cnt, pre, bsum, NN);
    scan_sums_k<<<dim3(1), dim3(64), 0, stream>>>(bsum, NB);
    scan_finalize_k<<<dim3((NN+255)/256), blk, 0, stream>>>(pre, bsum, offs, NN);
    fill_csr_k<<<dim3((EE+255)/256), blk, 0, stream>>>(dst, src, offs, cursor, eids, srcs_csr, EE);

    // fused edge projection, SEQUENTIAL rows, edge-order output:
    // [ep1|ep2] = ea @ [Wec1|Wec2] + [bec1|bec2]
    egemm_k<12,true,false,false><<<dim3(GB_E), dim3(512), 0, stream>>>(
        ea, 100, 100, Btep12, becf, epb1, 100, epb2, 80, 100, EE, 180);

    // x -> A'1[:,0:100]
    cvt_rows_k<<<dim3((int)(((long)NN*100 + 255)/256)), blk, 0, stream>>>(x, 100, Aprime1, KP1, (long)NN*100);

    // ---- conv1 (F=100) ----
    egemm_k<13,false,false,false><<<dim3(GB_N), dim3(512), 0, stream>>>(
        Aprime1, KP1, 0, Btij1, nullptr, xixjb, 200, nullptr, 0, 200, NN, 200);
    aggregate_k<100><<<dim3((NN+3)/4), blk, 0, stream>>>(
        xixjb, 200, epb1, eids, offs, srcs_csr, Aprime1 + 100, KP1, scl, avg_lin, avg_log, NN);
    mgemm_k<13><<<dim3((NN+127)/128, 2), blk, 0, stream>>>(
        Aprime1, KP1, Btpost1, KP1, Yb, 400, NN, KP1, 400);
    combine_k<<<dim3((NN*80+255)/256), blk, 0, stream>>>(Yb, scl, bpost1, tpost, NN*80);
    egemm_k<5,false,false,true><<<dim3(GB_N), dim3(512), 0, stream>>>(
        tpost, 128, 0, Btlin1, blin1, Aprime2, KP2, nullptr, 0, 80, NN, 80);

    // ---- conv2 (F=80) ----
    egemm_k<10,false,false,false><<<dim3(GB_N), dim3(512), 0, stream>>>(
        Aprime2, KP2, 0, Btij2, nullptr, xixjb, 160, nullptr, 0, 160, NN, 160);
    aggregate_k<80><<<dim3((NN+3)/4), blk, 0, stream>>>(
        xixjb, 160, epb2, eids, offs, srcs_csr, Aprime2 + 80, KP2, scl, avg_lin, avg_log, NN);
    mgemm_k<13><<<dim3((NN+127)/128, 2), blk, 0, stream>>>(
        Aprime2, KP2, Btpost2, KP2, Yb, 400, NN, KP2, 400);
    combine_k<<<dim3((NN*80+255)/256), blk, 0, stream>>>(Yb, scl, bpost2, tpost, NN*80);

    // ---- fused lin2∘fc1 (+relu), then fc2 ----
    egemm_k<5,false,false,true><<<dim3(GB_N), dim3(512), 0, stream>>>(
        tpost, 128, 0, Btlf, blf, tD, 128, nullptr, 0, 80, NN, 80);
    egemm_k<5,false,true,false><<<dim3(GB_N), dim3(512), 0, stream>>>(
        tD, 128, 0, Btfc2, bfc2, outb, 80, nullptr, 0, 80, NN, 80);
  }
}

// Round 6
// 2325.597 us; speedup vs baseline: 1.0031x; 1.0031x over previous
//
#include <hip/hip_runtime.h>
#include <cmath>

static constexpr int NN = 50000;   // nodes
static constexpr int EE = 500000;  // edges

typedef short v8s __attribute__((ext_vector_type(8)));
typedef short v4s __attribute__((ext_vector_type(4)));
typedef float v4f __attribute__((ext_vector_type(4)));

__device__ inline short f2bf(float x){
  union{float f; unsigned u;} v{x};
  unsigned r = v.u + 0x7fffu + ((v.u >> 16) & 1u);
  return (short)(r >> 16);
}
__device__ inline float b2f(short s){
  union{unsigned u; float f;} v; v.u = ((unsigned)(unsigned short)s) << 16; return v.f;
}

// ---------------- graph prep ----------------

__global__ __launch_bounds__(256)
void count_deg_k(const int* __restrict__ dst, int* __restrict__ cnt, int e_total){
  int e = blockIdx.x*256 + threadIdx.x;
  if (e < e_total) atomicAdd(&cnt[dst[e]], 1);
}

__global__ __launch_bounds__(1024)
void scan_block_k(const int* __restrict__ cnt, int* __restrict__ pre,
                  int* __restrict__ bsum, int n){
  __shared__ int tmp[1024];
  int b = blockIdx.x, t = threadIdx.x, i = b*1024 + t;
  int v = (i < n) ? cnt[i] : 0;
  tmp[t] = v; __syncthreads();
  for (int off = 1; off < 1024; off <<= 1){
    int u = (t >= off) ? tmp[t-off] : 0;
    __syncthreads();
    tmp[t] += u;
    __syncthreads();
  }
  if (i < n) pre[i] = tmp[t];
  if (t == 1023) bsum[b] = tmp[t];
}

__global__ void scan_sums_k(int* __restrict__ bsum, int nb){
  if (threadIdx.x == 0){
    int s = 0;
    for (int i = 0; i < nb; i++){ int v = bsum[i]; bsum[i] = s; s += v; }
  }
}

__global__ __launch_bounds__(256)
void scan_finalize_k(const int* __restrict__ pre, const int* __restrict__ bsum,
                     int* __restrict__ offs, int n){
  int i = blockIdx.x*256 + threadIdx.x;
  if (i < n) offs[i+1] = pre[i] + bsum[i >> 10];
  if (i == 0) offs[0] = 0;
}

__global__ __launch_bounds__(256)
void fill_csr_k(const int* __restrict__ dst, const int* __restrict__ src,
                const int* __restrict__ offs, int* __restrict__ cursor,
                int* __restrict__ eids, int* __restrict__ srcs_csr, int e_total){
  int e = blockIdx.x*256 + threadIdx.x;
  if (e < e_total){
    int d = dst[e];
    int p = offs[d] + atomicAdd(&cursor[d], 1);
    eids[p] = e;
    srcs_csr[p] = src[e];
  }
}

// ---------------- small fp32 helpers (weight prep) ----------------

__global__ __launch_bounds__(128)
void vecmat_bias_k(const float* __restrict__ v, const float* __restrict__ B,
                   const float* __restrict__ b2, float* __restrict__ out, int K, int Nc){
  int c = blockIdx.x*128 + threadIdx.x;
  if (c < Nc){
    float s = b2[c];
    for (int k = 0; k < K; k++) s += v[k]*B[(size_t)k*Nc + c];
    out[c] = s;
  }
}

__global__ __launch_bounds__(256)
void sgemm_k(const float* __restrict__ A, const float* __restrict__ B,
             float* __restrict__ C, int M, int K, int Nc){
  __shared__ float As[16][65];
  __shared__ float Bs[16][65];
  int bm = blockIdx.x*64, bn = blockIdx.y*64;
  int tid = threadIdx.x;
  int tx = tid & 15, ty = tid >> 4;
  float acc[4][4] = {};
  for (int k0 = 0; k0 < K; k0 += 16){
    #pragma unroll
    for (int i = 0; i < 4; i++){
      int t = tid + 256*i;
      int r = t >> 4, c = t & 15;
      int gr = bm + r, gc = k0 + c;
      As[c][r] = (gr < M && gc < K) ? A[(size_t)gr*K + gc] : 0.f;
    }
    #pragma unroll
    for (int i = 0; i < 4; i++){
      int t = tid + 256*i;
      int r = t >> 6, c = t & 63;
      int gr = k0 + r, gc = bn + c;
      Bs[r][c] = (gr < K && gc < Nc) ? B[(size_t)gr*Nc + gc] : 0.f;
    }
    __syncthreads();
    #pragma unroll
    for (int kk = 0; kk < 16; kk++){
      float a[4], b[4];
      #pragma unroll
      for (int i = 0; i < 4; i++) a[i] = As[kk][ty*4 + i];
      #pragma unroll
      for (int j = 0; j < 4; j++) b[j] = Bs[kk][tx*4 + j];
      #pragma unroll
      for (int i = 0; i < 4; i++)
        #pragma unroll
        for (int j = 0; j < 4; j++) acc[i][j] += a[i]*b[j];
    }
    __syncthreads();
  }
  #pragma unroll
  for (int i = 0; i < 4; i++){
    int gr = bm + ty*4 + i;
    if (gr >= M) continue;
    #pragma unroll
    for (int j = 0; j < 4; j++){
      int gc = bn + tx*4 + j;
      if (gc < Nc) C[(size_t)gr*Nc + gc] = acc[i][j];
    }
  }
}

// transpose+convert weights: dst[c][k] = src[k][c], bf16, zero-padded to Kpad
__global__ __launch_bounds__(256)
void tconv_k(const float* __restrict__ src, int K, int ldsrc, int Ncols,
             short* __restrict__ dst, int Kpad){
  int c = blockIdx.x;
  int k = blockIdx.y*256 + threadIdx.x;
  if (c < Ncols && k < Kpad)
    dst[(long)c*Kpad + k] = (k < K) ? f2bf(src[(long)k*ldsrc + c]) : (short)0;
}

// B' for post GEMM
__global__ __launch_bounds__(256)
void btpost_k(const float* __restrict__ Wpost, int F, int Kpad,
              short* __restrict__ dst){
  int cp = blockIdx.x;                 // 0..399
  int k = blockIdx.y*256 + threadIdx.x;
  if (k >= Kpad) return;
  int g = cp / 80, c = cp - g*80;
  float v = 0.f;
  if (k < F){ if (g == 0) v = Wpost[(long)k*80 + c]; }
  else if (k < 7*F) v = Wpost[(long)(F + g*6*F + (k - F))*80 + c];
  dst[(long)cp*Kpad + k] = f2bf(v);
}

__global__ __launch_bounds__(256)
void cvt_rows_k(const float* __restrict__ src, int K, short* __restrict__ dst,
                int ldd, long total){
  long i = (long)blockIdx.x*256 + threadIdx.x;
  if (i >= total) return;
  int n = (int)(i / K), c = (int)(i - (long)n*K);
  dst[(long)n*ldd + c] = f2bf(src[i]);
}

// ---------------- persistent-B MFMA GEMM (K <= 128, Bt: [ncols][128] bf16) ------
// A direct global->register fragments, SEQUENTIAL rows (no gather).
// Each wave owns 32 rows per tile; 8 waves/block; grid-stride over tiles.
// Output split: col < split -> C1 (C_F32 selects dtype), else C2 (bf16).
template<int NFR, bool A_F32, bool C_F32, bool RELU>
__global__ __launch_bounds__(512)
void egemm_k(const void* __restrict__ Av, long lda, int Kreal,
             const short* __restrict__ Bt, const float* __restrict__ bias,
             void* __restrict__ C1v, long ld1,
             short* __restrict__ C2, long ld2, int split,
             int M, int ncols)
{
  constexpr int BN = NFR*16;
  __shared__ short Bs[BN][136];
  const float* Af = (const float*)Av;
  const short* Ab = (const short*)Av;
  float* C1f = (float*)C1v; short* C1b = (short*)C1v;

  for (int u = threadIdx.x; u < BN*16; u += 512){
    int c = u >> 4, k8 = (u & 15)*8;
    v8s vv = (v8s)0;
    if (c < ncols) vv = *(const v8s*)(Bt + (long)c*128 + k8);
    *(v8s*)&Bs[c][k8] = vv;
  }
  __syncthreads();

  int lane = threadIdx.x & 63;
  int lr = lane & 15, lkg = lane >> 4;
  int w0 = (blockIdx.x*512 + threadIdx.x) >> 6;
  int nw = gridDim.x * 8;
  int Mtiles = (M + 31) >> 5;

  for (int t = w0; t < Mtiles; t += nw){
    int base = t*32;
    long r0 = base + lr;      if (r0 > M-1) r0 = M-1;
    long r1 = base + 16 + lr; if (r1 > M-1) r1 = M-1;

    v8s a0[4], a1[4];
    if constexpr (A_F32){
      const float* p0 = Af + r0*lda;
      const float* p1 = Af + r1*lda;
      #pragma unroll
      for (int ks = 0; ks < 4; ks++){
        int kb = ks*32 + lkg*8;
        v8s o0 = (v8s)0, o1 = (v8s)0;
        if (kb + 3 < Kreal){
          float4 f0 = *(const float4*)(p0 + kb);
          float4 f1 = *(const float4*)(p1 + kb);
          o0[0]=f2bf(f0.x); o0[1]=f2bf(f0.y); o0[2]=f2bf(f0.z); o0[3]=f2bf(f0.w);
          o1[0]=f2bf(f1.x); o1[1]=f2bf(f1.y); o1[2]=f2bf(f1.z); o1[3]=f2bf(f1.w);
        }
        if (kb + 7 < Kreal){
          float4 f0 = *(const float4*)(p0 + kb + 4);
          float4 f1 = *(const float4*)(p1 + kb + 4);
          o0[4]=f2bf(f0.x); o0[5]=f2bf(f0.y); o0[6]=f2bf(f0.z); o0[7]=f2bf(f0.w);
          o1[4]=f2bf(f1.x); o1[5]=f2bf(f1.y); o1[6]=f2bf(f1.z); o1[7]=f2bf(f1.w);
        }
        a0[ks] = o0; a1[ks] = o1;
      }
    } else {
      const short* p0 = Ab + r0*lda + lkg*8;
      const short* p1 = Ab + r1*lda + lkg*8;
      #pragma unroll
      for (int ks = 0; ks < 4; ks++){
        a0[ks] = *(const v8s*)(p0 + ks*32);
        a1[ks] = *(const v8s*)(p1 + ks*32);
      }
    }

    v4f acc0[NFR], acc1[NFR];
    #pragma unroll
    for (int n = 0; n < NFR; n++){ acc0[n] = (v4f)0.f; acc1[n] = (v4f)0.f; }
    #pragma unroll
    for (int ks = 0; ks < 4; ks++){
      #pragma unroll
      for (int n = 0; n < NFR; n++){
        v8s b = *(const v8s*)&Bs[n*16 + lr][ks*32 + lkg*8];
        acc0[n] = __builtin_amdgcn_mfma_f32_16x16x32_bf16(a0[ks], b, acc0[n], 0, 0, 0);
        acc1[n] = __builtin_amdgcn_mfma_f32_16x16x32_bf16(a1[ks], b, acc1[n], 0, 0, 0);
      }
    }
    // epilogue: col = n*16 + lr ; row = base + m*16 + lkg*4 + j
    #pragma unroll
    for (int n = 0; n < NFR; n++){
      int col = n*16 + lr;
      if (col >= ncols) continue;
      float bv = bias ? bias[col] : 0.f;
      #pragma unroll
      for (int j = 0; j < 4; j++){
        int row = base + lkg*4 + j;
        if (row < M){
          float v = acc0[n][j] + bv;
          if (RELU) v = fmaxf(v, 0.f);
          if (col < split){
            if constexpr (C_F32) C1f[(long)row*ld1 + col] = v;
            else                 C1b[(long)row*ld1 + col] = f2bf(v);
          } else C2[(long)row*ld2 + (col - split)] = f2bf(v);
        }
        int row1 = row + 16;
        if (row1 < M){
          float v = acc1[n][j] + bv;
          if (RELU) v = fmaxf(v, 0.f);
          if (col < split){
            if constexpr (C_F32) C1f[(long)row1*ld1 + col] = v;
            else                 C1b[(long)row1*ld1 + col] = f2bf(v);
          } else C2[(long)row1*ld2 + (col - split)] = f2bf(v);
        }
      }
    }
  }
}

// ---------------- MFMA GEMM with LDS A (for K>128: the post GEMMs) ----------------
template<int NFR>
__global__ __launch_bounds__(256)
void mgemm_k(const short* __restrict__ Ab, long lda,
             const short* __restrict__ Bt, int Kpad,
             short* __restrict__ Cb, long ldc, int M, int K, int Ncols)
{
  constexpr int BN = NFR*16;
  __shared__ short As[128][72];
  __shared__ short Bs[BN][72];

  int bm = blockIdx.x*128;
  int bn = blockIdx.y*BN;
  int tid = threadIdx.x;
  int w = tid >> 6, lane = tid & 63;
  int lr = lane & 15, lkg = lane >> 4;

  v4f acc[2][NFR];
  #pragma unroll
  for (int m = 0; m < 2; m++)
    #pragma unroll
    for (int n = 0; n < NFR; n++) acc[m][n] = (v4f)0.f;

  for (int k0 = 0; k0 < K; k0 += 64){
    #pragma unroll
    for (int p = 0; p < 4; p++){
      int u = tid + 256*p;
      int r = u >> 3, c8 = u & 7;
      int k = k0 + c8*8;
      int grow = bm + r;
      v8s out = (v8s)0;
      if (grow < M) out = *(const v8s*)(Ab + (long)grow*lda + k);
      *(v8s*)&As[r][c8*8] = out;
    }
    #pragma unroll
    for (int u0 = 0; u0 < BN*8; u0 += 256){
      int u = u0 + tid;
      if (u < BN*8){
        int c = u >> 3, k8 = (u & 7)*8;
        v8s out = (v8s)0;
        int gc = bn + c;
        if (gc < Ncols) out = *(const v8s*)(Bt + (long)gc*Kpad + k0 + k8);
        *(v8s*)&Bs[c][k8] = out;
      }
    }
    __syncthreads();
    #pragma unroll
    for (int ks = 0; ks < 2; ks++){
      v8s a0 = *(const v8s*)&As[w*32 + lr][ks*32 + lkg*8];
      v8s a1 = *(const v8s*)&As[w*32 + 16 + lr][ks*32 + lkg*8];
      #pragma unroll
      for (int n = 0; n < NFR; n++){
        v8s b = *(const v8s*)&Bs[n*16 + lr][ks*32 + lkg*8];
        acc[0][n] = __builtin_amdgcn_mfma_f32_16x16x32_bf16(a0, b, acc[0][n], 0, 0, 0);
        acc[1][n] = __builtin_amdgcn_mfma_f32_16x16x32_bf16(a1, b, acc[1][n], 0, 0, 0);
      }
    }
    __syncthreads();
  }
  #pragma unroll
  for (int m = 0; m < 2; m++){
    int row0 = bm + w*32 + m*16 + lkg*4;
    #pragma unroll
    for (int n = 0; n < NFR; n++){
      int col = bn + n*16 + lr;
      if (col >= Ncols) continue;
      #pragma unroll
      for (int j = 0; j < 4; j++){
        int row = row0 + j;
        if (row < M) Cb[(long)row*ldc + col] = f2bf(acc[m][n][j]);
      }
    }
  }
}

// ---------------- per-node aggregation (one wave per node) ----------------
// ep rows are in EDGE order; gathered via eids[p].
template<int F>
__global__ __launch_bounds__(256)
void aggregate_k(const short* __restrict__ xixj, int ldx,
                 const short* __restrict__ epc, const int* __restrict__ eids,
                 const int* __restrict__ offs, const int* __restrict__ srcs_csr,
                 short* __restrict__ aggout, long ldk,
                 float* __restrict__ scl, float avg_lin, float avg_log, int n){
  int wnode = (blockIdx.x*256 + threadIdx.x) >> 6;
  int lane = threadIdx.x & 63;
  if (wnode >= n) return;
  constexpr int C2 = F - 64;
  int beg = offs[wnode], end = offs[wnode+1];
  float xi0 = b2f(xixj[(long)wnode*ldx + lane]);
  float xi1 = (lane < C2) ? b2f(xixj[(long)wnode*ldx + 64 + lane]) : 0.f;
  float s0 = 0.f, q0 = 0.f, mn0 = INFINITY, mx0 = -INFINITY;
  float s1 = 0.f, q1 = 0.f, mn1 = INFINITY, mx1 = -INFINITY;
  for (int p = beg; p < end; p++){
    int s = srcs_csr[p];
    long e = eids[p];
    float h0 = xi0 + b2f(xixj[(long)s*ldx + F + lane]) + b2f(epc[e*F + lane]);
    s0 += h0; q0 += h0*h0; mn0 = fminf(mn0, h0); mx0 = fmaxf(mx0, h0);
    if (lane < C2){
      float h1 = xi1 + b2f(xixj[(long)s*ldx + F + 64 + lane]) + b2f(epc[e*F + 64 + lane]);
      s1 += h1; q1 += h1*h1; mn1 = fminf(mn1, h1); mx1 = fmaxf(mx1, h1);
    }
  }
  int cnt = end - beg;
  float deg = (float)(cnt > 1 ? cnt : 1);
  if (cnt == 0){ mn0 = 0.f; mx0 = 0.f; mn1 = 0.f; mx1 = 0.f; }
  float mean0 = s0/deg, var0 = q0/deg - mean0*mean0;
  float std0 = sqrtf(fmaxf(var0, 0.f) + 1e-5f);
  short* a = aggout + (long)wnode*ldk;
  a[lane] = f2bf(s0); a[F+lane] = f2bf(mean0); a[2*F+lane] = f2bf(mn0);
  a[3*F+lane] = f2bf(mx0); a[4*F+lane] = f2bf(var0); a[5*F+lane] = f2bf(std0);
  if (lane < C2){
    float mean1 = s1/deg, var1 = q1/deg - mean1*mean1;
    float std1 = sqrtf(fmaxf(var1, 0.f) + 1e-5f);
    int l2 = 64 + lane;
    a[l2] = f2bf(s1); a[F+l2] = f2bf(mean1); a[2*F+l2] = f2bf(mn1);
    a[3*F+l2] = f2bf(mx1); a[4*F+l2] = f2bf(var1); a[5*F+l2] = f2bf(std1);
  }
  if (lane == 0){
    float logd = logf(deg + 1.f);
    scl[wnode*5+0] = 1.f;
    scl[wnode*5+1] = logd/avg_log;
    scl[wnode*5+2] = avg_log/logd;
    scl[wnode*5+3] = deg/avg_lin;
    scl[wnode*5+4] = avg_lin/deg;
  }
}

// ---------------- combine: tpost[n][c] (ld 128) = bias[c] + sum_g scl[n][g]*Y[n][80g+c]
__global__ __launch_bounds__(256)
void combine_k(const short* __restrict__ Y, const float* __restrict__ scl,
               const float* __restrict__ bias, short* __restrict__ out, int total){
  int idx = blockIdx.x*256 + threadIdx.x;
  if (idx >= total) return;
  int n = idx / 80, c = idx - n*80;
  const short* y = Y + (long)n*400;
  const float* s = scl + (long)n*5;
  float v = bias[c];
  #pragma unroll
  for (int g = 0; g < 5; g++) v += s[g]*b2f(y[g*80 + c]);
  out[(long)n*128 + c] = f2bf(v);
}

// ---------------- host orchestration ----------------

extern "C" void kernel_launch(void* const* d_in, const int* in_sizes, int n_in,
                              void* d_out, int out_size, void* d_ws, size_t ws_size,
                              hipStream_t stream){
  const float* x1   = (const float*)d_in[0];
  const int*   ei1  = (const int*)  d_in[1];
  const float* ea1  = (const float*)d_in[2];
  const float* x2   = (const float*)d_in[3];
  const int*   ei2  = (const int*)  d_in[4];
  const float* ea2  = (const float*)d_in[5];
  const float* We1  = (const float*)d_in[6],  *be1   = (const float*)d_in[7];
  const float* Wpre1= (const float*)d_in[8],  *bpre1 = (const float*)d_in[9];
  const float* Wpost1=(const float*)d_in[10], *bpost1= (const float*)d_in[11];
  const float* Wlin1= (const float*)d_in[12], *blin1 = (const float*)d_in[13];
  const float* We2  = (const float*)d_in[14], *be2   = (const float*)d_in[15];
  const float* Wpre2= (const float*)d_in[16], *bpre2 = (const float*)d_in[17];
  const float* Wpost2=(const float*)d_in[18], *bpost2= (const float*)d_in[19];
  const float* Wlin2= (const float*)d_in[20], *blin2 = (const float*)d_in[21];
  const float* Wfc1 = (const float*)d_in[22], *bfc1  = (const float*)d_in[23];
  const float* Wfc2 = (const float*)d_in[24], *bfc2  = (const float*)d_in[25];

  static const double HIST[19] = {240,328,79,39,23,12,11,7,6,5,7,3,1,0,2,0,0,0,1};
  double tot = 0, lin = 0, lg = 0;
  for (int i = 0; i < 19; i++){ tot += HIST[i]; lin += i*HIST[i]; lg += log((double)i + 1.0)*HIST[i]; }
  float avg_lin = (float)(lin/tot), avg_log = (float)(lg/tot);

  const int KP1 = 704, KP2 = 576;   // post GEMM K paddings

  uintptr_t pw = (uintptr_t)d_ws;
  auto carve = [&](size_t b)->void*{ void* r = (void*)pw; pw += (b + 255) & ~(size_t)255; return r; };
  int*   cnt      = (int*)  carve((size_t)NN*4);
  int*   pre      = (int*)  carve((size_t)NN*4);
  int*   bsum     = (int*)  carve(64*4);
  int*   offs     = (int*)  carve((size_t)(NN+1)*4);
  int*   cursor   = (int*)  carve((size_t)NN*4);
  int*   eids     = (int*)  carve((size_t)EE*4);
  int*   srcs_csr = (int*)  carve((size_t)EE*4);
  float* WecA     = (float*)carve(100*100*4);
  float* WecB     = (float*)carve(100*80*4);
  float* Wlf      = (float*)carve(80*80*4);
  float* becf     = (float*)carve(256*4);
  float* blf      = (float*)carve(128*4);
  short* Btep12   = (short*)carve((size_t)180*128*2);
  short* Btij1    = (short*)carve((size_t)200*128*2);
  short* Btij2    = (short*)carve((size_t)160*128*2);
  short* Btpost1  = (short*)carve((size_t)400*KP1*2);
  short* Btpost2  = (short*)carve((size_t)400*KP2*2);
  short* Btlin1   = (short*)carve((size_t)80*128*2);
  short* Btlf     = (short*)carve((size_t)80*128*2);
  short* Btfc2    = (short*)carve((size_t)80*128*2);
  short* Aprime1  = (short*)carve((size_t)NN*KP1*2);   // [x(100) | agg(600) | pad]
  short* Aprime2  = (short*)carve((size_t)NN*KP2*2);   // [x(80)  | agg(480) | pad]
  short* xixjb    = (short*)carve((size_t)NN*200*2);
  short* epb1     = (short*)carve((size_t)EE*100*2);
  short* epb2     = (short*)carve((size_t)EE*80*2);
  float* scl      = (float*)carve((size_t)NN*5*4);
  short* Yb       = (short*)carve((size_t)NN*400*2);
  short* tpost    = (short*)carve((size_t)NN*128*2);
  short* tD       = (short*)carve((size_t)NN*128*2);

  dim3 blk(256);
  const int NB = (NN + 1023)/1024;
  const int NTILES = (NN + 31)/32;               // 1563
  const int GB_N  = (NTILES + 7)/8;              // node-GEMM blocks (1 tile/wave)
  const int GB_E  = 1024;                        // edge-GEMM blocks (grid-stride)

  // ---- weight prep ----
  sgemm_k<<<dim3(2,2), blk, 0, stream>>>(We1, Wpre1 + 2*100*100, WecA, 100, 100, 100);
  sgemm_k<<<dim3(2,2), blk, 0, stream>>>(We2, Wpre2 + 2*80*80,  WecB, 100, 80, 80);
  sgemm_k<<<dim3(2,2), blk, 0, stream>>>(Wlin2, Wfc1, Wlf, 80, 80, 80);
  vecmat_bias_k<<<dim3(1), dim3(128), 0, stream>>>(be1, Wpre1 + 2*100*100, bpre1, becf, 100, 100);
  vecmat_bias_k<<<dim3(1), dim3(128), 0, stream>>>(be2, Wpre2 + 2*80*80,  bpre2, becf + 100, 80, 80);
  vecmat_bias_k<<<dim3(1), dim3(128), 0, stream>>>(blin2, Wfc1, bfc1, blf, 80, 80);
  tconv_k<<<dim3(100,1), blk, 0, stream>>>(WecA, 100, 100, 100, Btep12, 128);
  tconv_k<<<dim3(80,1),  blk, 0, stream>>>(WecB, 100,  80,  80, Btep12 + 100*128, 128);
  tconv_k<<<dim3(100,1), blk, 0, stream>>>(Wpre1,           100, 100, 100, Btij1,           128);
  tconv_k<<<dim3(100,1), blk, 0, stream>>>(Wpre1 + 100*100, 100, 100, 100, Btij1 + 100*128, 128);
  tconv_k<<<dim3(80,1),  blk, 0, stream>>>(Wpre2,           80, 80, 80, Btij2,          128);
  tconv_k<<<dim3(80,1),  blk, 0, stream>>>(Wpre2 + 80*80,   80, 80, 80, Btij2 + 80*128, 128);
  btpost_k<<<dim3(400,(KP1+255)/256), blk, 0, stream>>>(Wpost1, 100, KP1, Btpost1);
  btpost_k<<<dim3(400,(KP2+255)/256), blk, 0, stream>>>(Wpost2,  80, KP2, Btpost2);
  tconv_k<<<dim3(80,1), blk, 0, stream>>>(Wlin1, 80, 80, 80, Btlin1, 128);
  tconv_k<<<dim3(80,1), blk, 0, stream>>>(Wlf,   80, 80, 80, Btlf,   128);
  tconv_k<<<dim3(80,1), blk, 0, stream>>>(Wfc2,  80, 80, 80, Btfc2,  128);
  // zero padded A-side buffers once (pad columns must stay 0)
  hipMemsetAsync(Aprime1, 0, (size_t)NN*KP1*2, stream);
  hipMemsetAsync(Aprime2, 0, (size_t)NN*KP2*2, stream);
  hipMemsetAsync(tpost,   0, (size_t)NN*128*2, stream);
  hipMemsetAsync(tD,      0, (size_t)NN*128*2, stream);

  for (int b = 0; b < 2; b++){
    const float* x  = b ? x2  : x1;
    const int*   ei = b ? ei2 : ei1;
    const float* ea = b ? ea2 : ea1;
    float* outb = (float*)d_out + (size_t)b*NN*80;
    const int* src = ei;
    const int* dst = ei + EE;

    // CSR
    hipMemsetAsync(cnt, 0, (size_t)NN*4, stream);
    hipMemsetAsync(cursor, 0, (size_t)NN*4, stream);
    count_deg_k<<<dim3((EE+255)/256), blk, 0, stream>>>(dst, cnt, EE);
    scan_block_k<<<dim3(NB), dim3(1024), 0, stream>>>(cnt, pre, bsum, NN);
    scan_sums_k<<<dim3(1), dim3(64), 0, stream>>>(bsum, NB);
    scan_finalize_k<<<dim3((NN+255)/256), blk, 0, stream>>>(pre, bsum, offs, NN);
    fill_csr_k<<<dim3((EE+255)/256), blk, 0, stream>>>(dst, src, offs, cursor, eids, srcs_csr, EE);

    // fused edge projection, SEQUENTIAL rows, edge-order output:
    // [ep1|ep2] = ea @ [Wec1|Wec2] + [bec1|bec2]
    egemm_k<12,true,false,false><<<dim3(GB_E), dim3(512), 0, stream>>>(
        ea, 100, 100, Btep12, becf, epb1, 100, epb2, 80, 100, EE, 180);

    // x -> A'1[:,0:100]
    cvt_rows_k<<<dim3((int)(((long)NN*100 + 255)/256)), blk, 0, stream>>>(x, 100, Aprime1, KP1, (long)NN*100);

    // ---- conv1 (F=100) ----
    egemm_k<13,false,false,false><<<dim3(GB_N), dim3(512), 0, stream>>>(
        Aprime1, KP1, 0, Btij1, nullptr, xixjb, 200, nullptr, 0, 200, NN, 200);
    aggregate_k<100><<<dim3((NN+3)/4), blk, 0, stream>>>(
        xixjb, 200, epb1, eids, offs, srcs_csr, Aprime1 + 100, KP1, scl, avg_lin, avg_log, NN);
    mgemm_k<13><<<dim3((NN+127)/128, 2), blk, 0, stream>>>(
        Aprime1, KP1, Btpost1, KP1, Yb, 400, NN, KP1, 400);
    combine_k<<<dim3((NN*80+255)/256), blk, 0, stream>>>(Yb, scl, bpost1, tpost, NN*80);
    egemm_k<5,false,false,true><<<dim3(GB_N), dim3(512), 0, stream>>>(
        tpost, 128, 0, Btlin1, blin1, Aprime2, KP2, nullptr, 0, 80, NN, 80);

    // ---- conv2 (F=80) ----
    egemm_k<10,false,false,false><<<dim3(GB_N), dim3(512), 0, stream>>>(
        Aprime2, KP2, 0, Btij2, nullptr, xixjb, 160, nullptr, 0, 160, NN, 160);
    aggregate_k<80><<<dim3((NN+3)/4), blk, 0, stream>>>(
        xixjb, 160, epb2, eids, offs, srcs_csr, Aprime2 + 80, KP2, scl, avg_lin, avg_log, NN);
    mgemm_k<13><<<dim3((NN+127)/128, 2), blk, 0, stream>>>(
        Aprime2, KP2, Btpost2, KP2, Yb, 400, NN, KP2, 400);
    combine_k<<<dim3((NN*80+255)/256), blk, 0, stream>>>(Yb, scl, bpost2, tpost, NN*80);

    // ---- fused lin2∘fc1 (+relu), then fc2 ----
    egemm_k<5,false,false,true><<<dim3(GB_N), dim3(512), 0, stream>>>(
        tpost, 128, 0, Btlf, blf, tD, 128, nullptr, 0, 80, NN, 80);
    egemm_k<5,false,true,false><<<dim3(GB_N), dim3(512), 0, stream>>>(
        tD, 128, 0, Btfc2, bfc2, outb, 80, nullptr, 0, 80, NN, 80);
  }
}

// Round 7
// 2325.292 us; speedup vs baseline: 1.0032x; 1.0001x over previous
//
#include <hip/hip_runtime.h>
#include <cmath>

static constexpr int NN = 50000;   // nodes
static constexpr int EE = 500000;  // edges

typedef short v8s __attribute__((ext_vector_type(8)));
typedef short v4s __attribute__((ext_vector_type(4)));
typedef float v4f __attribute__((ext_vector_type(4)));

__device__ inline short f2bf(float x){
  union{float f; unsigned u;} v{x};
  unsigned r = v.u + 0x7fffu + ((v.u >> 16) & 1u);
  return (short)(r >> 16);
}
__device__ inline float b2f(short s){
  union{unsigned u; float f;} v; v.u = ((unsigned)(unsigned short)s) << 16; return v.f;
}

// ---------------- graph prep ----------------

__global__ __launch_bounds__(256)
void count_deg_k(const int* __restrict__ dst, int* __restrict__ cnt, int e_total){
  int e = blockIdx.x*256 + threadIdx.x;
  if (e < e_total) atomicAdd(&cnt[dst[e]], 1);
}

__global__ __launch_bounds__(1024)
void scan_block_k(const int* __restrict__ cnt, int* __restrict__ pre,
                  int* __restrict__ bsum, int n){
  __shared__ int tmp[1024];
  int b = blockIdx.x, t = threadIdx.x, i = b*1024 + t;
  int v = (i < n) ? cnt[i] : 0;
  tmp[t] = v; __syncthreads();
  for (int off = 1; off < 1024; off <<= 1){
    int u = (t >= off) ? tmp[t-off] : 0;
    __syncthreads();
    tmp[t] += u;
    __syncthreads();
  }
  if (i < n) pre[i] = tmp[t];
  if (t == 1023) bsum[b] = tmp[t];
}

__global__ void scan_sums_k(int* __restrict__ bsum, int nb){
  if (threadIdx.x == 0){
    int s = 0;
    for (int i = 0; i < nb; i++){ int v = bsum[i]; bsum[i] = s; s += v; }
  }
}

__global__ __launch_bounds__(256)
void scan_finalize_k(const int* __restrict__ pre, const int* __restrict__ bsum,
                     int* __restrict__ offs, int n){
  int i = blockIdx.x*256 + threadIdx.x;
  if (i < n) offs[i+1] = pre[i] + bsum[i >> 10];
  if (i == 0) offs[0] = 0;
}

__global__ __launch_bounds__(256)
void fill_csr_k(const int* __restrict__ dst, const int* __restrict__ src,
                const int* __restrict__ offs, int* __restrict__ cursor,
                int* __restrict__ eids, int* __restrict__ srcs_csr, int e_total){
  int e = blockIdx.x*256 + threadIdx.x;
  if (e < e_total){
    int d = dst[e];
    int p = offs[d] + atomicAdd(&cursor[d], 1);
    eids[p] = e;
    srcs_csr[p] = src[e];
  }
}

// ---------------- small fp32 helpers (weight prep) ----------------

__global__ __launch_bounds__(128)
void vecmat_bias_k(const float* __restrict__ v, const float* __restrict__ B,
                   const float* __restrict__ b2, float* __restrict__ out, int K, int Nc){
  int c = blockIdx.x*128 + threadIdx.x;
  if (c < Nc){
    float s = b2[c];
    for (int k = 0; k < K; k++) s += v[k]*B[(size_t)k*Nc + c];
    out[c] = s;
  }
}

__global__ __launch_bounds__(256)
void sgemm_k(const float* __restrict__ A, const float* __restrict__ B,
             float* __restrict__ C, int M, int K, int Nc){
  __shared__ float As[16][65];
  __shared__ float Bs[16][65];
  int bm = blockIdx.x*64, bn = blockIdx.y*64;
  int tid = threadIdx.x;
  int tx = tid & 15, ty = tid >> 4;
  float acc[4][4] = {};
  for (int k0 = 0; k0 < K; k0 += 16){
    #pragma unroll
    for (int i = 0; i < 4; i++){
      int t = tid + 256*i;
      int r = t >> 4, c = t & 15;
      int gr = bm + r, gc = k0 + c;
      As[c][r] = (gr < M && gc < K) ? A[(size_t)gr*K + gc] : 0.f;
    }
    #pragma unroll
    for (int i = 0; i < 4; i++){
      int t = tid + 256*i;
      int r = t >> 6, c = t & 63;
      int gr = k0 + r, gc = bn + c;
      Bs[r][c] = (gr < K && gc < Nc) ? B[(size_t)gr*Nc + gc] : 0.f;
    }
    __syncthreads();
    #pragma unroll
    for (int kk = 0; kk < 16; kk++){
      float a[4], b[4];
      #pragma unroll
      for (int i = 0; i < 4; i++) a[i] = As[kk][ty*4 + i];
      #pragma unroll
      for (int j = 0; j < 4; j++) b[j] = Bs[kk][tx*4 + j];
      #pragma unroll
      for (int i = 0; i < 4; i++)
        #pragma unroll
        for (int j = 0; j < 4; j++) acc[i][j] += a[i]*b[j];
    }
    __syncthreads();
  }
  #pragma unroll
  for (int i = 0; i < 4; i++){
    int gr = bm + ty*4 + i;
    if (gr >= M) continue;
    #pragma unroll
    for (int j = 0; j < 4; j++){
      int gc = bn + tx*4 + j;
      if (gc < Nc) C[(size_t)gr*Nc + gc] = acc[i][j];
    }
  }
}

// transpose+convert weights: dst[c][k] = src[k][c], bf16, zero-padded to Kpad
__global__ __launch_bounds__(256)
void tconv_k(const float* __restrict__ src, int K, int ldsrc, int Ncols,
             short* __restrict__ dst, int Kpad){
  int c = blockIdx.x;
  int k = blockIdx.y*256 + threadIdx.x;
  if (c < Ncols && k < Kpad)
    dst[(long)c*Kpad + k] = (k < K) ? f2bf(src[(long)k*ldsrc + c]) : (short)0;
}

// B' for post GEMM
__global__ __launch_bounds__(256)
void btpost_k(const float* __restrict__ Wpost, int F, int Kpad,
              short* __restrict__ dst){
  int cp = blockIdx.x;                 // 0..399
  int k = blockIdx.y*256 + threadIdx.x;
  if (k >= Kpad) return;
  int g = cp / 80, c = cp - g*80;
  float v = 0.f;
  if (k < F){ if (g == 0) v = Wpost[(long)k*80 + c]; }
  else if (k < 7*F) v = Wpost[(long)(F + g*6*F + (k - F))*80 + c];
  dst[(long)cp*Kpad + k] = f2bf(v);
}

__global__ __launch_bounds__(256)
void cvt_rows_k(const float* __restrict__ src, int K, short* __restrict__ dst,
                int ldd, long total){
  long i = (long)blockIdx.x*256 + threadIdx.x;
  if (i >= total) return;
  int n = (int)(i / K), c = (int)(i - (long)n*K);
  dst[(long)n*ldd + c] = f2bf(src[i]);
}

// ---------------- persistent-B MFMA GEMM (K <= 128, Bt: [ncols][128] bf16) ------
// A direct global->register fragments, SEQUENTIAL rows (no gather).
// Each wave owns 32 rows per tile; 8 waves/block; grid-stride over tiles.
// Output split: col < split -> C1 (C_F32 selects dtype), else C2 (bf16).
template<int NFR, bool A_F32, bool C_F32, bool RELU>
__global__ __launch_bounds__(512)
void egemm_k(const void* __restrict__ Av, long lda, int Kreal,
             const short* __restrict__ Bt, const float* __restrict__ bias,
             void* __restrict__ C1v, long ld1,
             short* __restrict__ C2, long ld2, int split,
             int M, int ncols)
{
  constexpr int BN = NFR*16;
  __shared__ short Bs[BN][136];
  const float* Af = (const float*)Av;
  const short* Ab = (const short*)Av;
  float* C1f = (float*)C1v; short* C1b = (short*)C1v;

  for (int u = threadIdx.x; u < BN*16; u += 512){
    int c = u >> 4, k8 = (u & 15)*8;
    v8s vv = (v8s)0;
    if (c < ncols) vv = *(const v8s*)(Bt + (long)c*128 + k8);
    *(v8s*)&Bs[c][k8] = vv;
  }
  __syncthreads();

  int lane = threadIdx.x & 63;
  int lr = lane & 15, lkg = lane >> 4;
  int w0 = (blockIdx.x*512 + threadIdx.x) >> 6;
  int nw = gridDim.x * 8;
  int Mtiles = (M + 31) >> 5;

  for (int t = w0; t < Mtiles; t += nw){
    int base = t*32;
    long r0 = base + lr;      if (r0 > M-1) r0 = M-1;
    long r1 = base + 16 + lr; if (r1 > M-1) r1 = M-1;

    v8s a0[4], a1[4];
    if constexpr (A_F32){
      const float* p0 = Af + r0*lda;
      const float* p1 = Af + r1*lda;
      #pragma unroll
      for (int ks = 0; ks < 4; ks++){
        int kb = ks*32 + lkg*8;
        v8s o0 = (v8s)0, o1 = (v8s)0;
        if (kb + 3 < Kreal){
          float4 f0 = *(const float4*)(p0 + kb);
          float4 f1 = *(const float4*)(p1 + kb);
          o0[0]=f2bf(f0.x); o0[1]=f2bf(f0.y); o0[2]=f2bf(f0.z); o0[3]=f2bf(f0.w);
          o1[0]=f2bf(f1.x); o1[1]=f2bf(f1.y); o1[2]=f2bf(f1.z); o1[3]=f2bf(f1.w);
        }
        if (kb + 7 < Kreal){
          float4 f0 = *(const float4*)(p0 + kb + 4);
          float4 f1 = *(const float4*)(p1 + kb + 4);
          o0[4]=f2bf(f0.x); o0[5]=f2bf(f0.y); o0[6]=f2bf(f0.z); o0[7]=f2bf(f0.w);
          o1[4]=f2bf(f1.x); o1[5]=f2bf(f1.y); o1[6]=f2bf(f1.z); o1[7]=f2bf(f1.w);
        }
        a0[ks] = o0; a1[ks] = o1;
      }
    } else {
      const short* p0 = Ab + r0*lda + lkg*8;
      const short* p1 = Ab + r1*lda + lkg*8;
      #pragma unroll
      for (int ks = 0; ks < 4; ks++){
        a0[ks] = *(const v8s*)(p0 + ks*32);
        a1[ks] = *(const v8s*)(p1 + ks*32);
      }
    }

    v4f acc0[NFR], acc1[NFR];
    #pragma unroll
    for (int n = 0; n < NFR; n++){ acc0[n] = (v4f)0.f; acc1[n] = (v4f)0.f; }
    #pragma unroll
    for (int ks = 0; ks < 4; ks++){
      #pragma unroll
      for (int n = 0; n < NFR; n++){
        v8s b = *(const v8s*)&Bs[n*16 + lr][ks*32 + lkg*8];
        acc0[n] = __builtin_amdgcn_mfma_f32_16x16x32_bf16(a0[ks], b, acc0[n], 0, 0, 0);
        acc1[n] = __builtin_amdgcn_mfma_f32_16x16x32_bf16(a1[ks], b, acc1[n], 0, 0, 0);
      }
    }
    // epilogue: col = n*16 + lr ; row = base + m*16 + lkg*4 + j
    #pragma unroll
    for (int n = 0; n < NFR; n++){
      int col = n*16 + lr;
      if (col >= ncols) continue;
      float bv = bias ? bias[col] : 0.f;
      #pragma unroll
      for (int j = 0; j < 4; j++){
        int row = base + lkg*4 + j;
        if (row < M){
          float v = acc0[n][j] + bv;
          if (RELU) v = fmaxf(v, 0.f);
          if (col < split){
            if constexpr (C_F32) C1f[(long)row*ld1 + col] = v;
            else                 C1b[(long)row*ld1 + col] = f2bf(v);
          } else C2[(long)row*ld2 + (col - split)] = f2bf(v);
        }
        int row1 = row + 16;
        if (row1 < M){
          float v = acc1[n][j] + bv;
          if (RELU) v = fmaxf(v, 0.f);
          if (col < split){
            if constexpr (C_F32) C1f[(long)row1*ld1 + col] = v;
            else                 C1b[(long)row1*ld1 + col] = f2bf(v);
          } else C2[(long)row1*ld2 + (col - split)] = f2bf(v);
        }
      }
    }
  }
}

// ---------------- MFMA GEMM with LDS A (for K>128: the post GEMMs) ----------------
template<int NFR>
__global__ __launch_bounds__(256)
void mgemm_k(const short* __restrict__ Ab, long lda,
             const short* __restrict__ Bt, int Kpad,
             short* __restrict__ Cb, long ldc, int M, int K, int Ncols)
{
  constexpr int BN = NFR*16;
  __shared__ short As[128][72];
  __shared__ short Bs[BN][72];

  int bm = blockIdx.x*128;
  int bn = blockIdx.y*BN;
  int tid = threadIdx.x;
  int w = tid >> 6, lane = tid & 63;
  int lr = lane & 15, lkg = lane >> 4;

  v4f acc[2][NFR];
  #pragma unroll
  for (int m = 0; m < 2; m++)
    #pragma unroll
    for (int n = 0; n < NFR; n++) acc[m][n] = (v4f)0.f;

  for (int k0 = 0; k0 < K; k0 += 64){
    #pragma unroll
    for (int p = 0; p < 4; p++){
      int u = tid + 256*p;
      int r = u >> 3, c8 = u & 7;
      int k = k0 + c8*8;
      int grow = bm + r;
      v8s out = (v8s)0;
      if (grow < M) out = *(const v8s*)(Ab + (long)grow*lda + k);
      *(v8s*)&As[r][c8*8] = out;
    }
    #pragma unroll
    for (int u0 = 0; u0 < BN*8; u0 += 256){
      int u = u0 + tid;
      if (u < BN*8){
        int c = u >> 3, k8 = (u & 7)*8;
        v8s out = (v8s)0;
        int gc = bn + c;
        if (gc < Ncols) out = *(const v8s*)(Bt + (long)gc*Kpad + k0 + k8);
        *(v8s*)&Bs[c][k8] = out;
      }
    }
    __syncthreads();
    #pragma unroll
    for (int ks = 0; ks < 2; ks++){
      v8s a0 = *(const v8s*)&As[w*32 + lr][ks*32 + lkg*8];
      v8s a1 = *(const v8s*)&As[w*32 + 16 + lr][ks*32 + lkg*8];
      #pragma unroll
      for (int n = 0; n < NFR; n++){
        v8s b = *(const v8s*)&Bs[n*16 + lr][ks*32 + lkg*8];
        acc[0][n] = __builtin_amdgcn_mfma_f32_16x16x32_bf16(a0, b, acc[0][n], 0, 0, 0);
        acc[1][n] = __builtin_amdgcn_mfma_f32_16x16x32_bf16(a1, b, acc[1][n], 0, 0, 0);
      }
    }
    __syncthreads();
  }
  #pragma unroll
  for (int m = 0; m < 2; m++){
    int row0 = bm + w*32 + m*16 + lkg*4;
    #pragma unroll
    for (int n = 0; n < NFR; n++){
      int col = bn + n*16 + lr;
      if (col >= Ncols) continue;
      #pragma unroll
      for (int j = 0; j < 4; j++){
        int row = row0 + j;
        if (row < M) Cb[(long)row*ldc + col] = f2bf(acc[m][n][j]);
      }
    }
  }
}

// ---------------- per-node aggregation (one wave per node) ----------------
// ep rows are in EDGE order; gathered via eids[p].
template<int F>
__global__ __launch_bounds__(256)
void aggregate_k(const short* __restrict__ xixj, int ldx,
                 const short* __restrict__ epc, const int* __restrict__ eids,
                 const int* __restrict__ offs, const int* __restrict__ srcs_csr,
                 short* __restrict__ aggout, long ldk,
                 float* __restrict__ scl, float avg_lin, float avg_log, int n){
  int wnode = (blockIdx.x*256 + threadIdx.x) >> 6;
  int lane = threadIdx.x & 63;
  if (wnode >= n) return;
  constexpr int C2 = F - 64;
  int beg = offs[wnode], end = offs[wnode+1];
  float xi0 = b2f(xixj[(long)wnode*ldx + lane]);
  float xi1 = (lane < C2) ? b2f(xixj[(long)wnode*ldx + 64 + lane]) : 0.f;
  float s0 = 0.f, q0 = 0.f, mn0 = INFINITY, mx0 = -INFINITY;
  float s1 = 0.f, q1 = 0.f, mn1 = INFINITY, mx1 = -INFINITY;
  for (int p = beg; p < end; p++){
    int s = srcs_csr[p];
    long e = eids[p];
    float h0 = xi0 + b2f(xixj[(long)s*ldx + F + lane]) + b2f(epc[e*F + lane]);
    s0 += h0; q0 += h0*h0; mn0 = fminf(mn0, h0); mx0 = fmaxf(mx0, h0);
    if (lane < C2){
      float h1 = xi1 + b2f(xixj[(long)s*ldx + F + 64 + lane]) + b2f(epc[e*F + 64 + lane]);
      s1 += h1; q1 += h1*h1; mn1 = fminf(mn1, h1); mx1 = fmaxf(mx1, h1);
    }
  }
  int cnt = end - beg;
  float deg = (float)(cnt > 1 ? cnt : 1);
  if (cnt == 0){ mn0 = 0.f; mx0 = 0.f; mn1 = 0.f; mx1 = 0.f; }
  float mean0 = s0/deg, var0 = q0/deg - mean0*mean0;
  float std0 = sqrtf(fmaxf(var0, 0.f) + 1e-5f);
  short* a = aggout + (long)wnode*ldk;
  a[lane] = f2bf(s0); a[F+lane] = f2bf(mean0); a[2*F+lane] = f2bf(mn0);
  a[3*F+lane] = f2bf(mx0); a[4*F+lane] = f2bf(var0); a[5*F+lane] = f2bf(std0);
  if (lane < C2){
    float mean1 = s1/deg, var1 = q1/deg - mean1*mean1;
    float std1 = sqrtf(fmaxf(var1, 0.f) + 1e-5f);
    int l2 = 64 + lane;
    a[l2] = f2bf(s1); a[F+l2] = f2bf(mean1); a[2*F+l2] = f2bf(mn1);
    a[3*F+l2] = f2bf(mx1); a[4*F+l2] = f2bf(var1); a[5*F+l2] = f2bf(std1);
  }
  if (lane == 0){
    float logd = logf(deg + 1.f);
    scl[wnode*5+0] = 1.f;
    scl[wnode*5+1] = logd/avg_log;
    scl[wnode*5+2] = avg_log/logd;
    scl[wnode*5+3] = deg/avg_lin;
    scl[wnode*5+4] = avg_lin/deg;
  }
}

// ---------------- combine: tpost[n][c] (ld 128) = bias[c] + sum_g scl[n][g]*Y[n][80g+c]
__global__ __launch_bounds__(256)
void combine_k(const short* __restrict__ Y, const float* __restrict__ scl,
               const float* __restrict__ bias, short* __restrict__ out, int total){
  int idx = blockIdx.x*256 + threadIdx.x;
  if (idx >= total) return;
  int n = idx / 80, c = idx - n*80;
  const short* y = Y + (long)n*400;
  const float* s = scl + (long)n*5;
  float v = bias[c];
  #pragma unroll
  for (int g = 0; g < 5; g++) v += s[g]*b2f(y[g*80 + c]);
  out[(long)n*128 + c] = f2bf(v);
}

// ---------------- host orchestration ----------------

extern "C" void kernel_launch(void* const* d_in, const int* in_sizes, int n_in,
                              void* d_out, int out_size, void* d_ws, size_t ws_size,
                              hipStream_t stream){
  const float* x1   = (const float*)d_in[0];
  const int*   ei1  = (const int*)  d_in[1];
  const float* ea1  = (const float*)d_in[2];
  const float* x2   = (const float*)d_in[3];
  const int*   ei2  = (const int*)  d_in[4];
  const float* ea2  = (const float*)d_in[5];
  const float* We1  = (const float*)d_in[6],  *be1   = (const float*)d_in[7];
  const float* Wpre1= (const float*)d_in[8],  *bpre1 = (const float*)d_in[9];
  const float* Wpost1=(const float*)d_in[10], *bpost1= (const float*)d_in[11];
  const float* Wlin1= (const float*)d_in[12], *blin1 = (const float*)d_in[13];
  const float* We2  = (const float*)d_in[14], *be2   = (const float*)d_in[15];
  const float* Wpre2= (const float*)d_in[16], *bpre2 = (const float*)d_in[17];
  const float* Wpost2=(const float*)d_in[18], *bpost2= (const float*)d_in[19];
  const float* Wlin2= (const float*)d_in[20], *blin2 = (const float*)d_in[21];
  const float* Wfc1 = (const float*)d_in[22], *bfc1  = (const float*)d_in[23];
  const float* Wfc2 = (const float*)d_in[24], *bfc2  = (const float*)d_in[25];

  static const double HIST[19] = {240,328,79,39,23,12,11,7,6,5,7,3,1,0,2,0,0,0,1};
  double tot = 0, lin = 0, lg = 0;
  for (int i = 0; i < 19; i++){ tot += HIST[i]; lin += i*HIST[i]; lg += log((double)i + 1.0)*HIST[i]; }
  float avg_lin = (float)(lin/tot), avg_log = (float)(lg/tot);

  const int KP1 = 704, KP2 = 576;   // post GEMM K paddings

  uintptr_t pw = (uintptr_t)d_ws;
  auto carve = [&](size_t b)->void*{ void* r = (void*)pw; pw += (b + 255) & ~(size_t)255; return r; };
  int*   cnt      = (int*)  carve((size_t)NN*4);
  int*   pre      = (int*)  carve((size_t)NN*4);
  int*   bsum     = (int*)  carve(64*4);
  int*   offs     = (int*)  carve((size_t)(NN+1)*4);
  int*   cursor   = (int*)  carve((size_t)NN*4);
  int*   eids     = (int*)  carve((size_t)EE*4);
  int*   srcs_csr = (int*)  carve((size_t)EE*4);
  float* WecA     = (float*)carve(100*100*4);
  float* WecB     = (float*)carve(100*80*4);
  float* Wlf      = (float*)carve(80*80*4);
  float* becf     = (float*)carve(256*4);
  float* blf      = (float*)carve(128*4);
  short* Btep12   = (short*)carve((size_t)180*128*2);
  short* Btij1    = (short*)carve((size_t)200*128*2);
  short* Btij2    = (short*)carve((size_t)160*128*2);
  short* Btpost1  = (short*)carve((size_t)400*KP1*2);
  short* Btpost2  = (short*)carve((size_t)400*KP2*2);
  short* Btlin1   = (short*)carve((size_t)80*128*2);
  short* Btlf     = (short*)carve((size_t)80*128*2);
  short* Btfc2    = (short*)carve((size_t)80*128*2);
  short* Aprime1  = (short*)carve((size_t)NN*KP1*2);   // [x(100) | agg(600) | pad]
  short* Aprime2  = (short*)carve((size_t)NN*KP2*2);   // [x(80)  | agg(480) | pad]
  short* xixjb    = (short*)carve((size_t)NN*200*2);
  short* epb1     = (short*)carve((size_t)EE*100*2);
  short* epb2     = (short*)carve((size_t)EE*80*2);
  float* scl      = (float*)carve((size_t)NN*5*4);
  short* Yb       = (short*)carve((size_t)NN*400*2);
  short* tpost    = (short*)carve((size_t)NN*128*2);
  short* tD       = (short*)carve((size_t)NN*128*2);

  dim3 blk(256);
  const int NB = (NN + 1023)/1024;
  const int NTILES = (NN + 31)/32;               // 1563
  const int GB_N  = (NTILES + 7)/8;              // node-GEMM blocks (1 tile/wave)
  const int GB_E  = 1024;                        // edge-GEMM blocks (grid-stride)

  // ---- weight prep ----
  sgemm_k<<<dim3(2,2), blk, 0, stream>>>(We1, Wpre1 + 2*100*100, WecA, 100, 100, 100);
  sgemm_k<<<dim3(2,2), blk, 0, stream>>>(We2, Wpre2 + 2*80*80,  WecB, 100, 80, 80);
  sgemm_k<<<dim3(2,2), blk, 0, stream>>>(Wlin2, Wfc1, Wlf, 80, 80, 80);
  vecmat_bias_k<<<dim3(1), dim3(128), 0, stream>>>(be1, Wpre1 + 2*100*100, bpre1, becf, 100, 100);
  vecmat_bias_k<<<dim3(1), dim3(128), 0, stream>>>(be2, Wpre2 + 2*80*80,  bpre2, becf + 100, 80, 80);
  vecmat_bias_k<<<dim3(1), dim3(128), 0, stream>>>(blin2, Wfc1, bfc1, blf, 80, 80);
  tconv_k<<<dim3(100,1), blk, 0, stream>>>(WecA, 100, 100, 100, Btep12, 128);
  tconv_k<<<dim3(80,1),  blk, 0, stream>>>(WecB, 100,  80,  80, Btep12 + 100*128, 128);
  tconv_k<<<dim3(100,1), blk, 0, stream>>>(Wpre1,           100, 100, 100, Btij1,           128);
  tconv_k<<<dim3(100,1), blk, 0, stream>>>(Wpre1 + 100*100, 100, 100, 100, Btij1 + 100*128, 128);
  tconv_k<<<dim3(80,1),  blk, 0, stream>>>(Wpre2,           80, 80, 80, Btij2,          128);
  tconv_k<<<dim3(80,1),  blk, 0, stream>>>(Wpre2 + 80*80,   80, 80, 80, Btij2 + 80*128, 128);
  btpost_k<<<dim3(400,(KP1+255)/256), blk, 0, stream>>>(Wpost1, 100, KP1, Btpost1);
  btpost_k<<<dim3(400,(KP2+255)/256), blk, 0, stream>>>(Wpost2,  80, KP2, Btpost2);
  tconv_k<<<dim3(80,1), blk, 0, stream>>>(Wlin1, 80, 80, 80, Btlin1, 128);
  tconv_k<<<dim3(80,1), blk, 0, stream>>>(Wlf,   80, 80, 80, Btlf,   128);
  tconv_k<<<dim3(80,1), blk, 0, stream>>>(Wfc2,  80, 80, 80, Btfc2,  128);
  // zero padded A-side buffers once (pad columns must stay 0)
  hipMemsetAsync(Aprime1, 0, (size_t)NN*KP1*2, stream);
  hipMemsetAsync(Aprime2, 0, (size_t)NN*KP2*2, stream);
  hipMemsetAsync(tpost,   0, (size_t)NN*128*2, stream);
  hipMemsetAsync(tD,      0, (size_t)NN*128*2, stream);

  for (int b = 0; b < 2; b++){
    const float* x  = b ? x2  : x1;
    const int*   ei = b ? ei2 : ei1;
    const float* ea = b ? ea2 : ea1;
    float* outb = (float*)d_out + (size_t)b*NN*80;
    const int* src = ei;
    const int* dst = ei + EE;

    // CSR
    hipMemsetAsync(cnt, 0, (size_t)NN*4, stream);
    hipMemsetAsync(cursor, 0, (size_t)NN*4, stream);
    count_deg_k<<<dim3((EE+255)/256), blk, 0, stream>>>(dst, cnt, EE);
    scan_block_k<<<dim3(NB), dim3(1024), 0, stream>>>(cnt, pre, bsum, NN);
    scan_sums_k<<<dim3(1), dim3(64), 0, stream>>>(bsum, NB);
    scan_finalize_k<<<dim3((NN+255)/256), blk, 0, stream>>>(pre, bsum, offs, NN);
    fill_csr_k<<<dim3((EE+255)/256), blk, 0, stream>>>(dst, src, offs, cursor, eids, srcs_csr, EE);

    // fused edge projection, SEQUENTIAL rows, edge-order output:
    // [ep1|ep2] = ea @ [Wec1|Wec2] + [bec1|bec2]
    egemm_k<12,true,false,false><<<dim3(GB_E), dim3(512), 0, stream>>>(
        ea, 100, 100, Btep12, becf, epb1, 100, epb2, 80, 100, EE, 180);

    // x -> A'1[:,0:100]
    cvt_rows_k<<<dim3((int)(((long)NN*100 + 255)/256)), blk, 0, stream>>>(x, 100, Aprime1, KP1, (long)NN*100);

    // ---- conv1 (F=100) ----
    egemm_k<13,false,false,false><<<dim3(GB_N), dim3(512), 0, stream>>>(
        Aprime1, KP1, 0, Btij1, nullptr, xixjb, 200, nullptr, 0, 200, NN, 200);
    aggregate_k<100><<<dim3((NN+3)/4), blk, 0, stream>>>(
        xixjb, 200, epb1, eids, offs, srcs_csr, Aprime1 + 100, KP1, scl, avg_lin, avg_log, NN);
    mgemm_k<13><<<dim3((NN+127)/128, 2), blk, 0, stream>>>(
        Aprime1, KP1, Btpost1, KP1, Yb, 400, NN, KP1, 400);
    combine_k<<<dim3((NN*80+255)/256), blk, 0, stream>>>(Yb, scl, bpost1, tpost, NN*80);
    egemm_k<5,false,false,true><<<dim3(GB_N), dim3(512), 0, stream>>>(
        tpost, 128, 0, Btlin1, blin1, Aprime2, KP2, nullptr, 0, 80, NN, 80);

    // ---- conv2 (F=80) ----
    egemm_k<10,false,false,false><<<dim3(GB_N), dim3(512), 0, stream>>>(
        Aprime2, KP2, 0, Btij2, nullptr, xixjb, 160, nullptr, 0, 160, NN, 160);
    aggregate_k<80><<<dim3((NN+3)/4), blk, 0, stream>>>(
        xixjb, 160, epb2, eids, offs, srcs_csr, Aprime2 + 80, KP2, scl, avg_lin, avg_log, NN);
    mgemm_k<13><<<dim3((NN+127)/128, 2), blk, 0, stream>>>(
        Aprime2, KP2, Btpost2, KP2, Yb, 400, NN, KP2, 400);
    combine_k<<<dim3((NN*80+255)/256), blk, 0, stream>>>(Yb, scl, bpost2, tpost, NN*80);

    // ---- fused lin2∘fc1 (+relu), then fc2 ----
    egemm_k<5,false,false,true><<<dim3(GB_N), dim3(512), 0, stream>>>(
        tpost, 128, 0, Btlf, blf, tD, 128, nullptr, 0, 80, NN, 80);
    egemm_k<5,false,true,false><<<dim3(GB_N), dim3(512), 0, stream>>>(
        tD, 128, 0, Btfc2, bfc2, outb, 80, nullptr, 0, 80, NN, 80);
  }
}

// Round 8
// 1462.499 us; speedup vs baseline: 1.5950x; 1.5899x over previous
//
#include <hip/hip_runtime.h>
#include <cmath>

static constexpr int NN = 50000;   // nodes
static constexpr int EE = 500000;  // edges

typedef short v8s __attribute__((ext_vector_type(8)));
typedef float v4f __attribute__((ext_vector_type(4)));

__device__ inline short f2bf(float x){
  union{float f; unsigned u;} v{x};
  unsigned r = v.u + 0x7fffu + ((v.u >> 16) & 1u);
  return (short)(r >> 16);
}
__device__ inline float b2f(short s){
  union{unsigned u; float f;} v; v.u = ((unsigned)(unsigned short)s) << 16; return v.f;
}

// ---------------- graph prep ----------------

__global__ __launch_bounds__(256)
void count_deg_k(const int* __restrict__ dst, int* __restrict__ cnt, int e_total){
  int e = blockIdx.x*256 + threadIdx.x;
  if (e < e_total) atomicAdd(&cnt[dst[e]], 1);
}

__global__ __launch_bounds__(1024)
void scan_block_k(const int* __restrict__ cnt, int* __restrict__ pre,
                  int* __restrict__ bsum, int n){
  __shared__ int tmp[1024];
  int b = blockIdx.x, t = threadIdx.x, i = b*1024 + t;
  int v = (i < n) ? cnt[i] : 0;
  tmp[t] = v; __syncthreads();
  for (int off = 1; off < 1024; off <<= 1){
    int u = (t >= off) ? tmp[t-off] : 0;
    __syncthreads();
    tmp[t] += u;
    __syncthreads();
  }
  if (i < n) pre[i] = tmp[t];
  if (t == 1023) bsum[b] = tmp[t];
}

__global__ void scan_sums_k(int* __restrict__ bsum, int nb){
  if (threadIdx.x == 0){
    int s = 0;
    for (int i = 0; i < nb; i++){ int v = bsum[i]; bsum[i] = s; s += v; }
  }
}

__global__ __launch_bounds__(256)
void scan_finalize_k(const int* __restrict__ pre, const int* __restrict__ bsum,
                     int* __restrict__ offs, int n){
  int i = blockIdx.x*256 + threadIdx.x;
  if (i < n) offs[i+1] = pre[i] + bsum[i >> 10];
  if (i == 0) offs[0] = 0;
}

__global__ __launch_bounds__(256)
void fill_csr_k(const int* __restrict__ dst, const int* __restrict__ src,
                const int* __restrict__ offs, int* __restrict__ cursor,
                int* __restrict__ eids, int* __restrict__ srcs_csr, int e_total){
  int e = blockIdx.x*256 + threadIdx.x;
  if (e < e_total){
    int d = dst[e];
    int p = offs[d] + atomicAdd(&cursor[d], 1);
    eids[p] = e;
    srcs_csr[p] = src[e];
  }
}

// ---------------- small fp32 helpers (weight prep) ----------------

__global__ __launch_bounds__(128)
void vecmat_bias_k(const float* __restrict__ v, const float* __restrict__ B,
                   const float* __restrict__ b2, float* __restrict__ out, int K, int Nc){
  int c = blockIdx.x*128 + threadIdx.x;
  if (c < Nc){
    float s = b2[c];
    for (int k = 0; k < K; k++) s += v[k]*B[(size_t)k*Nc + c];
    out[c] = s;
  }
}

__global__ __launch_bounds__(256)
void sgemm_k(const float* __restrict__ A, const float* __restrict__ B,
             float* __restrict__ C, int M, int K, int Nc){
  __shared__ float As[16][65];
  __shared__ float Bs[16][65];
  int bm = blockIdx.x*64, bn = blockIdx.y*64;
  int tid = threadIdx.x;
  int tx = tid & 15, ty = tid >> 4;
  float acc[4][4] = {};
  for (int k0 = 0; k0 < K; k0 += 16){
    #pragma unroll
    for (int i = 0; i < 4; i++){
      int t = tid + 256*i;
      int r = t >> 4, c = t & 15;
      int gr = bm + r, gc = k0 + c;
      As[c][r] = (gr < M && gc < K) ? A[(size_t)gr*K + gc] : 0.f;
    }
    #pragma unroll
    for (int i = 0; i < 4; i++){
      int t = tid + 256*i;
      int r = t >> 6, c = t & 63;
      int gr = k0 + r, gc = bn + c;
      Bs[r][c] = (gr < K && gc < Nc) ? B[(size_t)gr*Nc + gc] : 0.f;
    }
    __syncthreads();
    #pragma unroll
    for (int kk = 0; kk < 16; kk++){
      float a[4], b[4];
      #pragma unroll
      for (int i = 0; i < 4; i++) a[i] = As[kk][ty*4 + i];
      #pragma unroll
      for (int j = 0; j < 4; j++) b[j] = Bs[kk][tx*4 + j];
      #pragma unroll
      for (int i = 0; i < 4; i++)
        #pragma unroll
        for (int j = 0; j < 4; j++) acc[i][j] += a[i]*b[j];
    }
    __syncthreads();
  }
  #pragma unroll
  for (int i = 0; i < 4; i++){
    int gr = bm + ty*4 + i;
    if (gr >= M) continue;
    #pragma unroll
    for (int j = 0; j < 4; j++){
      int gc = bn + tx*4 + j;
      if (gc < Nc) C[(size_t)gr*Nc + gc] = acc[i][j];
    }
  }
}

// transpose+convert weights: dst[c][k] = src[k][c], bf16, zero-padded to Kpad
__global__ __launch_bounds__(256)
void tconv_k(const float* __restrict__ src, int K, int ldsrc, int Ncols,
             short* __restrict__ dst, int Kpad){
  int c = blockIdx.x;
  int k = blockIdx.y*256 + threadIdx.x;
  if (c < Ncols && k < Kpad)
    dst[(long)c*Kpad + k] = (k < K) ? f2bf(src[(long)k*ldsrc + c]) : (short)0;
}

// B' for post GEMM
__global__ __launch_bounds__(256)
void btpost_k(const float* __restrict__ Wpost, int F, int Kpad,
              short* __restrict__ dst){
  int cp = blockIdx.x;                 // 0..399
  int k = blockIdx.y*256 + threadIdx.x;
  if (k >= Kpad) return;
  int g = cp / 80, c = cp - g*80;
  float v = 0.f;
  if (k < F){ if (g == 0) v = Wpost[(long)k*80 + c]; }
  else if (k < 7*F) v = Wpost[(long)(F + g*6*F + (k - F))*80 + c];
  dst[(long)cp*Kpad + k] = f2bf(v);
}

__global__ __launch_bounds__(256)
void cvt_rows_k(const float* __restrict__ src, int K, short* __restrict__ dst,
                int ldd, long total){
  long i = (long)blockIdx.x*256 + threadIdx.x;
  if (i >= total) return;
  int n = (int)(i / K), c = (int)(i - (long)n*K);
  dst[(long)n*ldd + c] = f2bf(src[i]);
}

// ---------------- persistent-B MFMA GEMM (K <= 128, Bt: [ncols][128] bf16) ------
// A direct global->register fragments, sequential rows. 8 waves/block, 32 rows
// per wave-tile, grid-stride over tiles. blockIdx.y slices columns by NFR*16.
// Epilogue: per-wave LDS stage -> v8s full-line coalesced stores (the fix for
// the 5x write amplification of 2-byte fragment stores).
template<int NFR, bool A_F32, bool C_F32, bool RELU>
__global__ __launch_bounds__(512)
void egemm_k(const void* __restrict__ Av, long lda, int Kreal,
             const short* __restrict__ Bt, const float* __restrict__ bias,
             void* __restrict__ Cv, long ldc, int M, int ncols)
{
  constexpr int BN = NFR*16;
  constexpr int PITCH = NFR*16 + 8;       // stage pitch (shorts), 16B-aligned rows
  constexpr int NCH = 2*NFR;              // v8s chunks per row
  __shared__ short Bs[BN][136];
  __shared__ short stage[8*16*PITCH];
  const float* Af = (const float*)Av;
  const short* Ab = (const short*)Av;
  short* Cb = (short*)Cv;
  float* Cf = (float*)Cv;

  int bn = blockIdx.y*BN;
  for (int u = threadIdx.x; u < BN*16; u += 512){
    int c = u >> 4, k8 = (u & 15)*8;
    v8s vv = (v8s)0;
    if (bn + c < ncols) vv = *(const v8s*)(Bt + (long)(bn + c)*128 + k8);
    *(v8s*)&Bs[c][k8] = vv;
  }
  __syncthreads();

  int lane = threadIdx.x & 63;
  int lr = lane & 15, lkg = lane >> 4;
  int w = threadIdx.x >> 6;
  short* st = stage + w*16*PITCH;
  int w0 = (blockIdx.x*512 + threadIdx.x) >> 6;
  int nw = gridDim.x * 8;
  int Mtiles = (M + 31) >> 5;

  for (int t = w0; t < Mtiles; t += nw){
    int base = t*32;
    long r0 = base + lr;      if (r0 > M-1) r0 = M-1;
    long r1 = base + 16 + lr; if (r1 > M-1) r1 = M-1;

    v8s a0[4], a1[4];
    if constexpr (A_F32){
      const float* p0 = Af + r0*lda;
      const float* p1 = Af + r1*lda;
      #pragma unroll
      for (int ks = 0; ks < 4; ks++){
        int kb = ks*32 + lkg*8;
        v8s o0 = (v8s)0, o1 = (v8s)0;
        if (kb + 3 < Kreal){
          float4 f0 = *(const float4*)(p0 + kb);
          float4 f1 = *(const float4*)(p1 + kb);
          o0[0]=f2bf(f0.x); o0[1]=f2bf(f0.y); o0[2]=f2bf(f0.z); o0[3]=f2bf(f0.w);
          o1[0]=f2bf(f1.x); o1[1]=f2bf(f1.y); o1[2]=f2bf(f1.z); o1[3]=f2bf(f1.w);
        }
        if (kb + 7 < Kreal){
          float4 f0 = *(const float4*)(p0 + kb + 4);
          float4 f1 = *(const float4*)(p1 + kb + 4);
          o0[4]=f2bf(f0.x); o0[5]=f2bf(f0.y); o0[6]=f2bf(f0.z); o0[7]=f2bf(f0.w);
          o1[4]=f2bf(f1.x); o1[5]=f2bf(f1.y); o1[6]=f2bf(f1.z); o1[7]=f2bf(f1.w);
        }
        a0[ks] = o0; a1[ks] = o1;
      }
    } else {
      const short* p0 = Ab + r0*lda + lkg*8;
      const short* p1 = Ab + r1*lda + lkg*8;
      #pragma unroll
      for (int ks = 0; ks < 4; ks++){
        a0[ks] = *(const v8s*)(p0 + ks*32);
        a1[ks] = *(const v8s*)(p1 + ks*32);
      }
    }

    v4f acc0[NFR], acc1[NFR];
    #pragma unroll
    for (int n = 0; n < NFR; n++){ acc0[n] = (v4f)0.f; acc1[n] = (v4f)0.f; }
    #pragma unroll
    for (int ks = 0; ks < 4; ks++){
      #pragma unroll
      for (int n = 0; n < NFR; n++){
        v8s b = *(const v8s*)&Bs[n*16 + lr][ks*32 + lkg*8];
        acc0[n] = __builtin_amdgcn_mfma_f32_16x16x32_bf16(a0[ks], b, acc0[n], 0, 0, 0);
        acc1[n] = __builtin_amdgcn_mfma_f32_16x16x32_bf16(a1[ks], b, acc1[n], 0, 0, 0);
      }
    }

    if constexpr (C_F32){
      #pragma unroll
      for (int n = 0; n < NFR; n++){
        int col = bn + n*16 + lr;
        if (col >= ncols) continue;
        float bv = bias ? bias[col] : 0.f;
        #pragma unroll
        for (int j = 0; j < 4; j++){
          int row = base + lkg*4 + j;
          float v0 = acc0[n][j] + bv;
          float v1 = acc1[n][j] + bv;
          if (RELU){ v0 = fmaxf(v0, 0.f); v1 = fmaxf(v1, 0.f); }
          if (row < M)      Cf[(long)row*ldc + col] = v0;
          if (row + 16 < M) Cf[(long)(row+16)*ldc + col] = v1;
        }
      }
    } else {
      #pragma unroll
      for (int half = 0; half < 2; half++){
        #pragma unroll
        for (int n = 0; n < NFR; n++){
          float bv = bias ? bias[bn + n*16 + lr] : 0.f;
          #pragma unroll
          for (int j = 0; j < 4; j++){
            float v = (half ? acc1[n][j] : acc0[n][j]) + bv;
            if (RELU) v = fmaxf(v, 0.f);
            st[(lkg*4 + j)*PITCH + n*16 + lr] = f2bf(v);
          }
        }
        int rb = base + half*16;
        #pragma unroll
        for (int i = 0; i < (16*NCH + 63)/64; i++){
          int c = i*64 + lane;
          if (c < 16*NCH){
            int r = c/NCH, off = (c - r*NCH)*8;
            int grow = rb + r;
            if (grow < M)
              *(v8s*)(Cb + (long)grow*ldc + bn + off) = *(const v8s*)&st[r*PITCH + off];
          }
        }
      }
    }
  }
}

// ---------------- fused post GEMM + scale combine ----------------
// out[n][c] = bpost[c] + sum_g scl[n][g] * ([x|agg] @ Btpost^T)[n][80g+c]
// 8 waves x 16 rows; each wave computes all 400 cols (25 frags); 80 = 5*16 so
// the g-combine is lane-local register math. Output tpost ld 128 via LDS stage.
__global__ __launch_bounds__(512)
void pgemm_k(const short* __restrict__ Ab, int kpad,
             const short* __restrict__ Bt, const float* __restrict__ scl,
             const float* __restrict__ bias, short* __restrict__ C, int M)
{
  __shared__ short Bs[400][40];
  __shared__ short AsSt[10240];   // union: As[128][40] (5120) | stage 8*16*80
  short (*As)[40] = (short(*)[40])AsSt;

  int tid = threadIdx.x;
  int w = tid >> 6, lane = tid & 63;
  int lr = lane & 15, lkg = lane >> 4;
  int bm = blockIdx.x*128;

  v4f acc[25];
  #pragma unroll
  for (int n = 0; n < 25; n++) acc[n] = (v4f)0.f;

  for (int k0 = 0; k0 < kpad; k0 += 32){
    {
      int u = tid;
      int r = u >> 2, c8 = (u & 3)*8;
      int grow = bm + r;
      v8s out = (v8s)0;
      if (grow < M) out = *(const v8s*)(Ab + (long)grow*kpad + k0 + c8);
      *(v8s*)&As[r][c8] = out;
    }
    for (int u = tid; u < 400*4; u += 512){
      int c = u >> 2, k8 = (u & 3)*8;
      *(v8s*)&Bs[c][k8] = *(const v8s*)(Bt + (long)c*kpad + k0 + k8);
    }
    __syncthreads();
    {
      v8s a = *(const v8s*)&As[w*16 + lr][lkg*8];
      #pragma unroll
      for (int n = 0; n < 25; n++){
        v8s b = *(const v8s*)&Bs[n*16 + lr][lkg*8];
        acc[n] = __builtin_amdgcn_mfma_f32_16x16x32_bf16(a, b, acc[n], 0, 0, 0);
      }
    }
    __syncthreads();
  }

  // combine + staged write (stage reuses As space; last sync above protects it)
  short* st = AsSt + w*16*80;
  float sc[4][5];
  #pragma unroll
  for (int j = 0; j < 4; j++){
    int row = bm + w*16 + lkg*4 + j;
    int rr = row < M ? row : 0;
    #pragma unroll
    for (int g = 0; g < 5; g++) sc[j][g] = scl[rr*5 + g];
  }
  #pragma unroll
  for (int cc = 0; cc < 5; cc++){
    float bv = bias[cc*16 + lr];
    #pragma unroll
    for (int j = 0; j < 4; j++){
      float v = bv;
      #pragma unroll
      for (int g = 0; g < 5; g++) v += sc[j][g]*acc[5*g + cc][j];
      st[(lkg*4 + j)*80 + cc*16 + lr] = f2bf(v);
    }
  }
  #pragma unroll
  for (int i = 0; i < 3; i++){
    int c = i*64 + lane;
    if (c < 160){
      int r = c/10, off = (c - r*10)*8;
      int grow = bm + w*16 + r;
      if (grow < M)
        *(v8s*)(C + (long)grow*128 + off) = *(const v8s*)&st[r*80 + off];
    }
  }
}

// ---------------- per-node aggregation (one wave per node) ----------------
// ep rows are in EDGE order in a combined [EE][192] buffer; gathered via eids.
template<int F>
__global__ __launch_bounds__(256)
void aggregate_k(const short* __restrict__ xixj, int ldx,
                 const short* __restrict__ epc, int epoff,
                 const int* __restrict__ eids,
                 const int* __restrict__ offs, const int* __restrict__ srcs_csr,
                 short* __restrict__ aggout, long ldk,
                 float* __restrict__ scl, float avg_lin, float avg_log, int n){
  int wnode = (blockIdx.x*256 + threadIdx.x) >> 6;
  int lane = threadIdx.x & 63;
  if (wnode >= n) return;
  constexpr int C2 = F - 64;
  int beg = offs[wnode], end = offs[wnode+1];
  float xi0 = b2f(xixj[(long)wnode*ldx + lane]);
  float xi1 = (lane < C2) ? b2f(xixj[(long)wnode*ldx + 64 + lane]) : 0.f;
  float s0 = 0.f, q0 = 0.f, mn0 = INFINITY, mx0 = -INFINITY;
  float s1 = 0.f, q1 = 0.f, mn1 = INFINITY, mx1 = -INFINITY;
  for (int p = beg; p < end; p++){
    int s = srcs_csr[p];
    long e = eids[p];
    float h0 = xi0 + b2f(xixj[(long)s*ldx + F + lane]) + b2f(epc[e*192 + epoff + lane]);
    s0 += h0; q0 += h0*h0; mn0 = fminf(mn0, h0); mx0 = fmaxf(mx0, h0);
    if (lane < C2){
      float h1 = xi1 + b2f(xixj[(long)s*ldx + F + 64 + lane]) + b2f(epc[e*192 + epoff + 64 + lane]);
      s1 += h1; q1 += h1*h1; mn1 = fminf(mn1, h1); mx1 = fmaxf(mx1, h1);
    }
  }
  int cnt = end - beg;
  float deg = (float)(cnt > 1 ? cnt : 1);
  if (cnt == 0){ mn0 = 0.f; mx0 = 0.f; mn1 = 0.f; mx1 = 0.f; }
  float mean0 = s0/deg, var0 = q0/deg - mean0*mean0;
  float std0 = sqrtf(fmaxf(var0, 0.f) + 1e-5f);
  short* a = aggout + (long)wnode*ldk;
  a[lane] = f2bf(s0); a[F+lane] = f2bf(mean0); a[2*F+lane] = f2bf(mn0);
  a[3*F+lane] = f2bf(mx0); a[4*F+lane] = f2bf(var0); a[5*F+lane] = f2bf(std0);
  if (lane < C2){
    float mean1 = s1/deg, var1 = q1/deg - mean1*mean1;
    float std1 = sqrtf(fmaxf(var1, 0.f) + 1e-5f);
    int l2 = 64 + lane;
    a[l2] = f2bf(s1); a[F+l2] = f2bf(mean1); a[2*F+l2] = f2bf(mn1);
    a[3*F+l2] = f2bf(mx1); a[4*F+l2] = f2bf(var1); a[5*F+l2] = f2bf(std1);
  }
  if (lane == 0){
    float logd = logf(deg + 1.f);
    scl[wnode*5+0] = 1.f;
    scl[wnode*5+1] = logd/avg_log;
    scl[wnode*5+2] = avg_log/logd;
    scl[wnode*5+3] = deg/avg_lin;
    scl[wnode*5+4] = avg_lin/deg;
  }
}

// ---------------- host orchestration ----------------

extern "C" void kernel_launch(void* const* d_in, const int* in_sizes, int n_in,
                              void* d_out, int out_size, void* d_ws, size_t ws_size,
                              hipStream_t stream){
  const float* x1   = (const float*)d_in[0];
  const int*   ei1  = (const int*)  d_in[1];
  const float* ea1  = (const float*)d_in[2];
  const float* x2   = (const float*)d_in[3];
  const int*   ei2  = (const int*)  d_in[4];
  const float* ea2  = (const float*)d_in[5];
  const float* We1  = (const float*)d_in[6],  *be1   = (const float*)d_in[7];
  const float* Wpre1= (const float*)d_in[8],  *bpre1 = (const float*)d_in[9];
  const float* Wpost1=(const float*)d_in[10], *bpost1= (const float*)d_in[11];
  const float* Wlin1= (const float*)d_in[12], *blin1 = (const float*)d_in[13];
  const float* We2  = (const float*)d_in[14], *be2   = (const float*)d_in[15];
  const float* Wpre2= (const float*)d_in[16], *bpre2 = (const float*)d_in[17];
  const float* Wpost2=(const float*)d_in[18], *bpost2= (const float*)d_in[19];
  const float* Wlin2= (const float*)d_in[20], *blin2 = (const float*)d_in[21];
  const float* Wfc1 = (const float*)d_in[22], *bfc1  = (const float*)d_in[23];
  const float* Wfc2 = (const float*)d_in[24], *bfc2  = (const float*)d_in[25];

  static const double HIST[19] = {240,328,79,39,23,12,11,7,6,5,7,3,1,0,2,0,0,0,1};
  double tot = 0, lin = 0, lg = 0;
  for (int i = 0; i < 19; i++){ tot += HIST[i]; lin += i*HIST[i]; lg += log((double)i + 1.0)*HIST[i]; }
  float avg_lin = (float)(lin/tot), avg_log = (float)(lg/tot);

  const int KP1 = 704, KP2 = 576;   // post GEMM K paddings

  uintptr_t pw = (uintptr_t)d_ws;
  auto carve = [&](size_t b)->void*{ void* r = (void*)pw; pw += (b + 255) & ~(size_t)255; return r; };
  int*   cnt      = (int*)  carve((size_t)NN*4);
  int*   pre      = (int*)  carve((size_t)NN*4);
  int*   bsum     = (int*)  carve(64*4);
  int*   offs     = (int*)  carve((size_t)(NN+1)*4);
  int*   cursor   = (int*)  carve((size_t)NN*4);
  int*   eids     = (int*)  carve((size_t)EE*4);
  int*   srcs_csr = (int*)  carve((size_t)EE*4);
  float* WecA     = (float*)carve(100*100*4);
  float* WecB     = (float*)carve(100*80*4);
  float* Wlf      = (float*)carve(80*80*4);
  float* becf     = (float*)carve(256*4);
  float* blf      = (float*)carve(128*4);
  short* Btep12   = (short*)carve((size_t)192*128*2);
  short* Btij1    = (short*)carve((size_t)208*128*2);
  short* Btij2    = (short*)carve((size_t)160*128*2);
  short* Btpost1  = (short*)carve((size_t)400*KP1*2);
  short* Btpost2  = (short*)carve((size_t)400*KP2*2);
  short* Btlin1   = (short*)carve((size_t)80*128*2);
  short* Btlf     = (short*)carve((size_t)80*128*2);
  short* Btfc2    = (short*)carve((size_t)80*128*2);
  short* Aprime1  = (short*)carve((size_t)NN*KP1*2);   // [x(100) | agg(600) | pad]
  short* Aprime2  = (short*)carve((size_t)NN*KP2*2);   // [x(80)  | agg(480) | pad]
  short* xixjb    = (short*)carve((size_t)NN*224*2);
  short* epc      = (short*)carve((size_t)EE*192*2);   // [ep1(100) | ep2(80) | pad]
  float* scl      = (float*)carve((size_t)NN*5*4);
  short* tpost    = (short*)carve((size_t)NN*128*2);
  short* tD       = (short*)carve((size_t)NN*128*2);

  dim3 blk(256);
  const int NB = (NN + 1023)/1024;
  const int NTILES = (NN + 31)/32;               // 1563
  const int GB_N  = (NTILES + 7)/8;              // node-GEMM blocks (1 tile/wave)
  const int GB_E  = 512;                         // edge-GEMM blocks (grid-stride)

  // ---- weight prep ----
  sgemm_k<<<dim3(2,2), blk, 0, stream>>>(We1, Wpre1 + 2*100*100, WecA, 100, 100, 100);
  sgemm_k<<<dim3(2,2), blk, 0, stream>>>(We2, Wpre2 + 2*80*80,  WecB, 100, 80, 80);
  sgemm_k<<<dim3(2,2), blk, 0, stream>>>(Wlin2, Wfc1, Wlf, 80, 80, 80);
  hipMemsetAsync(becf, 0, 256*4, stream);
  vecmat_bias_k<<<dim3(1), dim3(128), 0, stream>>>(be1, Wpre1 + 2*100*100, bpre1, becf, 100, 100);
  vecmat_bias_k<<<dim3(1), dim3(128), 0, stream>>>(be2, Wpre2 + 2*80*80,  bpre2, becf + 100, 80, 80);
  vecmat_bias_k<<<dim3(1), dim3(128), 0, stream>>>(blin2, Wfc1, bfc1, blf, 80, 80);
  tconv_k<<<dim3(100,1), blk, 0, stream>>>(WecA, 100, 100, 100, Btep12, 128);
  tconv_k<<<dim3(80,1),  blk, 0, stream>>>(WecB, 100,  80,  80, Btep12 + 100*128, 128);
  hipMemsetAsync(Btep12 + 180*128, 0, (size_t)12*128*2, stream);
  tconv_k<<<dim3(100,1), blk, 0, stream>>>(Wpre1,           100, 100, 100, Btij1,           128);
  tconv_k<<<dim3(100,1), blk, 0, stream>>>(Wpre1 + 100*100, 100, 100, 100, Btij1 + 100*128, 128);
  hipMemsetAsync(Btij1 + 200*128, 0, (size_t)8*128*2, stream);
  tconv_k<<<dim3(80,1),  blk, 0, stream>>>(Wpre2,           80, 80, 80, Btij2,          128);
  tconv_k<<<dim3(80,1),  blk, 0, stream>>>(Wpre2 + 80*80,   80, 80, 80, Btij2 + 80*128, 128);
  btpost_k<<<dim3(400,(KP1+255)/256), blk, 0, stream>>>(Wpost1, 100, KP1, Btpost1);
  btpost_k<<<dim3(400,(KP2+255)/256), blk, 0, stream>>>(Wpost2,  80, KP2, Btpost2);
  tconv_k<<<dim3(80,1), blk, 0, stream>>>(Wlin1, 80, 80, 80, Btlin1, 128);
  tconv_k<<<dim3(80,1), blk, 0, stream>>>(Wlf,   80, 80, 80, Btlf,   128);
  tconv_k<<<dim3(80,1), blk, 0, stream>>>(Wfc2,  80, 80, 80, Btfc2,  128);
  // zero padded A-side buffers once (pad regions must be finite; B pad rows are
  // zero so pad values multiply by 0, but NaN*0=NaN -> keep them zeroed)
  hipMemsetAsync(Aprime1, 0, (size_t)NN*KP1*2, stream);
  hipMemsetAsync(Aprime2, 0, (size_t)NN*KP2*2, stream);
  hipMemsetAsync(tpost,   0, (size_t)NN*128*2, stream);
  hipMemsetAsync(tD,      0, (size_t)NN*128*2, stream);

  for (int b = 0; b < 2; b++){
    const float* x  = b ? x2  : x1;
    const int*   ei = b ? ei2 : ei1;
    const float* ea = b ? ea2 : ea1;
    float* outb = (float*)d_out + (size_t)b*NN*80;
    const int* src = ei;
    const int* dst = ei + EE;

    // CSR
    hipMemsetAsync(cnt, 0, (size_t)NN*4, stream);
    hipMemsetAsync(cursor, 0, (size_t)NN*4, stream);
    count_deg_k<<<dim3((EE+255)/256), blk, 0, stream>>>(dst, cnt, EE);
    scan_block_k<<<dim3(NB), dim3(1024), 0, stream>>>(cnt, pre, bsum, NN);
    scan_sums_k<<<dim3(1), dim3(64), 0, stream>>>(bsum, NB);
    scan_finalize_k<<<dim3((NN+255)/256), blk, 0, stream>>>(pre, bsum, offs, NN);
    fill_csr_k<<<dim3((EE+255)/256), blk, 0, stream>>>(dst, src, offs, cursor, eids, srcs_csr, EE);

    // fused edge projection, sequential rows, edge-order combined output:
    // epc[:, :180] = ea @ [Wec1|Wec2] + [bec1|bec2]   (cols split over grid.y)
    egemm_k<6,true,false,false><<<dim3(GB_E,2), dim3(512), 0, stream>>>(
        ea, 100, 100, Btep12, becf, epc, 192, EE, 180);

    // x -> A'1[:,0:100]
    cvt_rows_k<<<dim3((int)(((long)NN*100 + 255)/256)), blk, 0, stream>>>(x, 100, Aprime1, KP1, (long)NN*100);

    // ---- conv1 (F=100) ----
    egemm_k<7,false,false,false><<<dim3(GB_N,2), dim3(512), 0, stream>>>(
        Aprime1, KP1, 0, Btij1, nullptr, xixjb, 224, NN, 200);
    aggregate_k<100><<<dim3((NN+3)/4), blk, 0, stream>>>(
        xixjb, 224, epc, 0, eids, offs, srcs_csr, Aprime1 + 100, KP1, scl, avg_lin, avg_log, NN);
    pgemm_k<<<dim3((NN+127)/128), dim3(512), 0, stream>>>(
        Aprime1, KP1, Btpost1, scl, bpost1, tpost, NN);
    egemm_k<5,false,false,true><<<dim3(GB_N), dim3(512), 0, stream>>>(
        tpost, 128, 0, Btlin1, blin1, Aprime2, KP2, NN, 80);

    // ---- conv2 (F=80) ----
    egemm_k<5,false,false,false><<<dim3(GB_N,2), dim3(512), 0, stream>>>(
        Aprime2, KP2, 0, Btij2, nullptr, xixjb, 160, NN, 160);
    aggregate_k<80><<<dim3((NN+3)/4), blk, 0, stream>>>(
        xixjb, 160, epc, 100, eids, offs, srcs_csr, Aprime2 + 80, KP2, scl, avg_lin, avg_log, NN);
    pgemm_k<<<dim3((NN+127)/128), dim3(512), 0, stream>>>(
        Aprime2, KP2, Btpost2, scl, bpost2, tpost, NN);

    // ---- fused lin2∘fc1 (+relu), then fc2 ----
    egemm_k<5,false,false,true><<<dim3(GB_N), dim3(512), 0, stream>>>(
        tpost, 128, 0, Btlf, blf, tD, 128, NN, 80);
    egemm_k<5,false,true,false><<<dim3(GB_N), dim3(512), 0, stream>>>(
        tD, 128, 0, Btfc2, bfc2, outb, 80, NN, 80);
  }
}